// Round 7
// baseline (244.963 us; speedup 1.0000x reference)
//
#include <hip/hip_runtime.h>

typedef __bf16 bf16;
typedef __bf16 bf16x8 __attribute__((ext_vector_type(8)));
typedef float f32x4 __attribute__((ext_vector_type(4)));

typedef __attribute__((address_space(1))) const void as1_void;
typedef __attribute__((address_space(3))) void as3_void;

#define DEV __device__ __forceinline__
#define NEG_BIG (-1.0e30f)

// B=2, T=2048, C=1024, H=16, D=64; M = B*T = 4096

DEV void async_load16(const void* g, void* l) {
  __builtin_amdgcn_global_load_lds((as1_void*)g, (as3_void*)l, 16, 0, 0);
}
DEV bf16x8 load8(const bf16* p) { bf16x8 v; __builtin_memcpy(&v, p, 16); return v; }
DEV void store8(bf16* p, bf16x8 v) { __builtin_memcpy(p, &v, 16); }
// raw v_exp_f32 (2^x). Non-volatile asm: schedulable, kept live by use.
DEV float fexp2(float x) { float r; asm("v_exp_f32 %0, %1" : "=v"(r) : "v"(x)); return r; }

// ---------------- in-kernel dtype sniff (block-uniform, deterministic) ----------------
DEV int sniff_bf16(const unsigned short* __restrict__ xr) {
  const int lane = threadIdx.x & 63;
  const unsigned short w = xr[lane * 2];
  const int e = (w >> 7) & 0xFF;
  const bool sane = ((w & 0x7FFF) == 0) || (e >= 97 && e <= 157);
  return __popcll(__ballot(sane)) >= 48;
}

// ---------------- input canonicalization (-> bf16, row-major) ----------------
struct ConvArgs {
  const void* src[6];
  bf16* dst[6];
  int n[6];
};

__global__ __launch_bounds__(256) void convert_kernel(ConvArgs a) {
  const int isbf = sniff_bf16((const unsigned short*)a.src[0]);
  const int t = blockIdx.y;
  const int n = a.n[t];
  bf16* d = a.dst[t];
  const int stride = gridDim.x * 256 * 8;
  if (isbf) {
    const bf16* s = (const bf16*)a.src[t];
    for (int i = (blockIdx.x * 256 + threadIdx.x) * 8; i < n; i += stride)
      store8(d + i, load8(s + i));
  } else {
    const float* s = (const float*)a.src[t];
    for (int i = (blockIdx.x * 256 + threadIdx.x) * 8; i < n; i += stride) {
      float tmp[8];
      __builtin_memcpy(tmp, s + i, 32);
      bf16x8 v;
#pragma unroll
      for (int j = 0; j < 8; ++j) v[j] = (bf16)tmp[j];
      store8(d + i, v);
    }
  }
}

// ---------------- GEMM core v3: BK=32, 3 LDS buffers, 1 barrier/K-tile ----------------
// (unchanged, verified r3)
DEV void gemm_core_128_p(const bf16* A, const bf16* W, const int K, int m0, int n0,
                         f32x4 (&acc)[4][4]) {
  __shared__ alignas(16) bf16 As[3][128 * 32];
  __shared__ alignas(16) bf16 Bs[3][128 * 32];
  const int tid = threadIdx.x;
  const int lane = tid & 63;
  const int wid = tid >> 6;
  const int wm = (wid >> 1) << 6;
  const int wn = (wid & 1) << 6;
  const int lr = lane & 15;
  const int lg = lane >> 4;

  size_t srcA[2], srcB[2];
  int ldsoff[2];
#pragma unroll
  for (int it = 0; it < 2; ++it) {
    const int lin = it * 256 + tid;        // 16B chunk id, 0..511
    const int lr2 = lin >> 3, c = lin & 7;
    const int u = c ^ (lr2 & 7);
    const int r = lr2 * 2 + (u >> 2);      // source row 0..127
    const int g = u & 3;                   // source k-group (8 elems)
    srcA[it] = (size_t)(m0 + r) * K + (size_t)(g * 8);
    srcB[it] = (size_t)(n0 + r) * K + (size_t)(g * 8);
    ldsoff[it] = lin * 8;
  }
  int offA[4], offB[4];
#pragma unroll
  for (int i = 0; i < 4; ++i) {
    const int r = wm + i * 16 + lr;
    const int cc = (lg | ((r & 1) << 2)) ^ ((r >> 1) & 7);
    offA[i] = (((r >> 1) << 3) | cc) * 8;
  }
#pragma unroll
  for (int j = 0; j < 4; ++j) {
    const int r = wn + j * 16 + lr;
    const int cc = (lg | ((r & 1) << 2)) ^ ((r >> 1) & 7);
    offB[j] = (((r >> 1) << 3) | cc) * 8;
  }

  const f32x4 zero = {0.f, 0.f, 0.f, 0.f};
#pragma unroll
  for (int i = 0; i < 4; ++i)
#pragma unroll
    for (int j = 0; j < 4; ++j) acc[i][j] = zero;

  const int nt = K >> 5;  // 32

  auto stage = [&](int buf, int t) {
    const size_t k0 = (size_t)(t << 5);
#pragma unroll
    for (int it = 0; it < 2; ++it) {
      async_load16(A + srcA[it] + k0, &As[buf][0] + ldsoff[it]);
      async_load16(W + srcB[it] + k0, &Bs[buf][0] + ldsoff[it]);
    }
  };

  auto compute = [&](int buf) {
    const bf16* as = &As[buf][0];
    const bf16* bs = &Bs[buf][0];
    bf16x8 af[4], bfr[4];
#pragma unroll
    for (int i = 0; i < 4; ++i) af[i] = load8(as + offA[i]);
#pragma unroll
    for (int j = 0; j < 4; ++j) bfr[j] = load8(bs + offB[j]);
    __builtin_amdgcn_s_setprio(1);
#pragma unroll
    for (int i = 0; i < 4; ++i)
#pragma unroll
      for (int j = 0; j < 4; ++j)
        acc[i][j] = __builtin_amdgcn_mfma_f32_16x16x32_bf16(af[i], bfr[j], acc[i][j], 0, 0, 0);
    __builtin_amdgcn_s_setprio(0);
  };

  stage(0, 0);
  stage(1, 1);
  int b0 = 0, b1 = 1, b2 = 2;
  for (int t = 0; t < nt; ++t) {
    if (t + 1 < nt) asm volatile("s_waitcnt vmcnt(4)" ::: "memory");
    else            asm volatile("s_waitcnt vmcnt(0)" ::: "memory");
    __builtin_amdgcn_s_barrier();          // all waves' tile-t portions in LDS
    if (t + 2 < nt) stage(b2, t + 2);      // buffer last read at iter t-1: safe
    compute(b0);
    const int tmp = b0; b0 = b1; b1 = b2; b2 = tmp;
  }
}

// ---------------- GEMM core: 128x64 tile variant (for out_proj grid-512) -----------
// Same pipeline; per wave 64x32 output (acc[4][2]); 3 loads/thread/tile -> vmcnt(3).
DEV void gemm_core_128x64_p(const bf16* A, const bf16* W, const int K, int m0, int n0,
                            f32x4 (&acc)[4][2]) {
  __shared__ alignas(16) bf16 As[3][128 * 32];
  __shared__ alignas(16) bf16 Bs[3][64 * 32];
  const int tid = threadIdx.x;
  const int lane = tid & 63;
  const int wid = tid >> 6;
  const int wm = (wid >> 1) << 6;
  const int wn = (wid & 1) << 5;
  const int lr = lane & 15;
  const int lg = lane >> 4;

  size_t srcA[2], srcB;
  int ldsoffA[2], ldsoffB;
#pragma unroll
  for (int it = 0; it < 2; ++it) {
    const int lin = it * 256 + tid;        // A: 512 chunks
    const int lr2 = lin >> 3, c = lin & 7;
    const int u = c ^ (lr2 & 7);
    srcA[it] = (size_t)(m0 + lr2 * 2 + (u >> 2)) * K + (size_t)((u & 3) * 8);
    ldsoffA[it] = lin * 8;
  }
  {
    const int lin = tid;                   // B: 256 chunks (64 rows)
    const int lr2 = lin >> 3, c = lin & 7;
    const int u = c ^ (lr2 & 7);
    srcB = (size_t)(n0 + lr2 * 2 + (u >> 2)) * K + (size_t)((u & 3) * 8);
    ldsoffB = lin * 8;
  }
  int offA[4], offB[2];
#pragma unroll
  for (int i = 0; i < 4; ++i) {
    const int r = wm + i * 16 + lr;
    const int cc = (lg | ((r & 1) << 2)) ^ ((r >> 1) & 7);
    offA[i] = (((r >> 1) << 3) | cc) * 8;
  }
#pragma unroll
  for (int j = 0; j < 2; ++j) {
    const int r = wn + j * 16 + lr;
    const int cc = (lg | ((r & 1) << 2)) ^ ((r >> 1) & 7);
    offB[j] = (((r >> 1) << 3) | cc) * 8;
  }

  const f32x4 zero = {0.f, 0.f, 0.f, 0.f};
#pragma unroll
  for (int i = 0; i < 4; ++i)
#pragma unroll
    for (int j = 0; j < 2; ++j) acc[i][j] = zero;

  const int nt = K >> 5;  // 32

  auto stage = [&](int buf, int t) {
    const size_t k0 = (size_t)(t << 5);
#pragma unroll
    for (int it = 0; it < 2; ++it)
      async_load16(A + srcA[it] + k0, &As[buf][0] + ldsoffA[it]);
    async_load16(W + srcB + k0, &Bs[buf][0] + ldsoffB);
  };

  auto compute = [&](int buf) {
    const bf16* as = &As[buf][0];
    const bf16* bs = &Bs[buf][0];
    bf16x8 af[4], bfr[2];
#pragma unroll
    for (int i = 0; i < 4; ++i) af[i] = load8(as + offA[i]);
#pragma unroll
    for (int j = 0; j < 2; ++j) bfr[j] = load8(bs + offB[j]);
    __builtin_amdgcn_s_setprio(1);
#pragma unroll
    for (int i = 0; i < 4; ++i)
#pragma unroll
      for (int j = 0; j < 2; ++j)
        acc[i][j] = __builtin_amdgcn_mfma_f32_16x16x32_bf16(af[i], bfr[j], acc[i][j], 0, 0, 0);
    __builtin_amdgcn_s_setprio(0);
  };

  stage(0, 0);
  stage(1, 1);
  int b0 = 0, b1 = 1, b2 = 2;
  for (int t = 0; t < nt; ++t) {
    if (t + 1 < nt) asm volatile("s_waitcnt vmcnt(3)" ::: "memory");
    else            asm volatile("s_waitcnt vmcnt(0)" ::: "memory");
    __builtin_amdgcn_s_barrier();
    if (t + 2 < nt) stage(b2, t + 2);
    compute(b0);
    const int tmp = b0; b0 = b1; b1 = b2; b2 = tmp;
  }
}

// Fragment-order address for a 64x64 tile, element (row, col):
DEV size_t frag_idx(int row, int col) {
  return ((size_t)(((col >> 5) * 4 + ((row >> 4) & 3)) * 64 + ((col >> 3) & 3) * 16 + (row & 15)) << 3)
         | (size_t)(col & 7);
}

// 1-D grid 768. Q pre-scaled by 0.125*log2(e) so attn uses raw v_exp_f32.
__global__ __launch_bounds__(256) void qkv_proj_kernel(
    const bf16* __restrict__ x, const bf16* __restrict__ Wq,
    const bf16* __restrict__ Wk, const bf16* __restrict__ Wv,
    bf16* __restrict__ q_ws, bf16* __restrict__ k_ws, bf16* __restrict__ vt_ws) {
  const int L = blockIdx.x;
  const int xcd = L & 7;
  const int i2 = L >> 3;                 // 0..95
  const int m0 = (xcd * 4 + (i2 & 3)) << 7;
  const int rest = i2 >> 2;              // 0..23
  const int n0 = (rest & 7) << 7;
  const int mode = rest >> 3;            // 0..2
  const bf16* W = (mode == 0) ? Wq : (mode == 1) ? Wk : Wv;
  f32x4 acc[4][4];
  gemm_core_128_p(x, W, 1024, m0, n0, acc);

  const int tid = threadIdx.x;
  const int lane = tid & 63, wid = tid >> 6;
  const int wm = (wid >> 1) << 6, wn = (wid & 1) << 6;
  const int lr = lane & 15, lg = lane >> 4;
  bf16* out = (mode == 0) ? q_ws : (mode == 1) ? k_ws : vt_ws;
  const float scale = (mode == 0) ? 0.18033688011112042f : 1.0f;  // 0.125*log2e
#pragma unroll
  for (int i = 0; i < 4; ++i) {
#pragma unroll
    for (int r = 0; r < 4; ++r) {
      const int m = m0 + wm + i * 16 + lg * 4 + r;
      const int b = m >> 11, t = m & 2047;
#pragma unroll
      for (int j = 0; j < 4; ++j) {
        const int n = n0 + wn + j * 16 + lr;
        const int h = n >> 6, d = n & 63;
        const float v = acc[i][j][r] * scale;
        const size_t base = ((size_t)(b * 16 + h) << 17) + ((size_t)(t >> 6) << 12);
        const size_t idx = base + ((mode < 2) ? frag_idx(t & 63, d) : frag_idx(d, t & 63));
        out[idx] = (bf16)v;
      }
    }
  }
}

// Flash attention v8: = v6 but 2 K/V buffers (LDS 41 KB -> 3 blocks/CU) + exp2.
__global__ __launch_bounds__(256, 3) void attn_kernel(
    const bf16* __restrict__ q_ws, const bf16* __restrict__ k_ws,
    const bf16* __restrict__ vt_ws, bf16* __restrict__ a_ws) {
  const int L = blockIdx.x;
  const int bh = (L & 7) * 4 + ((L >> 3) & 3);
  const int qt = 31 - (L >> 5);
  const int tid = threadIdx.x;
  const int lane = tid & 63, w = tid >> 6;
  const int lr = lane & 15, lg = lane >> 4;
  const int fo = lg * 16 + lr;

  __shared__ alignas(16) bf16 Ks[2][4096];
  __shared__ alignas(16) bf16 Vs[2][4096];
  __shared__ alignas(16) bf16 Ps[4][16 * 72];
  bf16* ps = &Ps[w][0];

  const size_t hb = (size_t)bh << 17;
  const int b = bh >> 4, h = bh & 15;
  const f32x4 zero = {0.f, 0.f, 0.f, 0.f};
  const bf16* kbase = k_ws + hb;
  const bf16* vbase = vt_ws + hb;
  const size_t qtb = hb + ((size_t)qt << 12);

  bf16x8 aq[2];
#pragma unroll
  for (int c2 = 0; c2 < 2; ++c2)
    aq[c2] = load8(q_ws + qtb + (size_t)(((c2 * 4 + w) * 64 + fo) << 3));

  f32x4 o_acc[4];
#pragma unroll
  for (int j = 0; j < 4; ++j) o_acc[j] = zero;
  float lsum[4] = {0.f, 0.f, 0.f, 0.f};

  const int nt = qt + 1;
  auto ktof = [&](int s) { return (s == 0) ? qt : (s - 1); };

  auto stage = [&](int buf, int s) {
    const int kt = ktof(s);
    const bf16* kg = kbase + ((size_t)kt << 12);
    const bf16* vg = vbase + ((size_t)kt << 12);
#pragma unroll
    for (int it = 0; it < 2; ++it) {
      const int lin = it * 256 + tid;
      async_load16(kg + lin * 8, &Ks[buf][0] + lin * 8);
      async_load16(vg + lin * 8, &Vs[buf][0] + lin * 8);
    }
  };

  auto step = [&](int buf, bool diag) {
    const bf16* ks = &Ks[buf][0];
    const bf16* vs = &Vs[buf][0];
    f32x4 s[4];
    __builtin_amdgcn_s_setprio(1);
#pragma unroll
    for (int j = 0; j < 4; ++j) {
      s[j] = __builtin_amdgcn_mfma_f32_16x16x32_bf16(
          aq[0], load8(ks + (size_t)(((0 * 4 + j) * 64 + fo) << 3)), zero, 0, 0, 0);
      s[j] = __builtin_amdgcn_mfma_f32_16x16x32_bf16(
          aq[1], load8(ks + (size_t)(((1 * 4 + j) * 64 + fo) << 3)), s[j], 0, 0, 0);
    }
    __builtin_amdgcn_s_setprio(0);
    float p[4][4];
#pragma unroll
    for (int j = 0; j < 4; ++j) {
#pragma unroll
      for (int r = 0; r < 4; ++r) {
        float v = s[j][r];
        if (diag && (j * 16 + lr) > (w * 16 + lg * 4 + r)) v = NEG_BIG;
        p[j][r] = fexp2(v);
      }
    }
#pragma unroll
    for (int r = 0; r < 4; ++r)
      lsum[r] += (p[0][r] + p[1][r]) + (p[2][r] + p[3][r]);
#pragma unroll
    for (int j = 0; j < 4; ++j)
#pragma unroll
      for (int r = 0; r < 4; ++r)
        ps[(lg * 4 + r) * 72 + j * 16 + lr] = (bf16)p[j][r];
    __builtin_amdgcn_s_setprio(1);
#pragma unroll
    for (int c2 = 0; c2 < 2; ++c2) {
      const bf16x8 ap = load8(ps + lr * 72 + c2 * 32 + lg * 8);
#pragma unroll
      for (int j = 0; j < 4; ++j)
        o_acc[j] = __builtin_amdgcn_mfma_f32_16x16x32_bf16(
            ap, load8(vs + (size_t)(((c2 * 4 + j) * 64 + fo) << 3)), o_acc[j], 0, 0, 0);
    }
    __builtin_amdgcn_s_setprio(0);
  };

  // 2-buffer, distance-1, 1 barrier/step. stage(cur^1, t+1) is issued after
  // barrier(t): all waves have consumed their step t-1 reads of that buffer.
  stage(0, 0);
  int cur = 0;
  for (int t = 0; t < nt; ++t) {
    asm volatile("s_waitcnt vmcnt(0)" ::: "memory");
    __builtin_amdgcn_s_barrier();
    if (t + 1 < nt) stage(cur ^ 1, t + 1);
    step(cur, t == 0);
    cur ^= 1;
  }

#pragma unroll
  for (int r = 0; r < 4; ++r) {
    float v = lsum[r];
#pragma unroll
    for (int off = 1; off < 16; off <<= 1) v += __shfl_xor(v, off, 64);
    const float inv = 1.f / v;
    const int t = qt * 64 + w * 16 + lg * 4 + r;
#pragma unroll
    for (int j = 0; j < 4; ++j) {
      const size_t idx = (((size_t)(b * 2048 + t)) << 10) | (size_t)(h * 64 + j * 16 + lr);
      a_ws[idx] = (bf16)(o_acc[j][r] * inv);
    }
  }
}

// DIAG 1: identical to attn v8 but NO P LDS round-trip (PV consumes aq regs;
// p kept live via lsum). Isolates the P-strip write->read cost. Scratch out.
__global__ __launch_bounds__(256, 3) void attn_diag_noP(
    const bf16* __restrict__ q_ws, const bf16* __restrict__ k_ws,
    const bf16* __restrict__ vt_ws, bf16* __restrict__ a_ws) {
  const int L = blockIdx.x;
  const int bh = (L & 7) * 4 + ((L >> 3) & 3);
  const int qt = 31 - (L >> 5);
  const int tid = threadIdx.x;
  const int lane = tid & 63, w = tid >> 6;
  const int lr = lane & 15, lg = lane >> 4;
  const int fo = lg * 16 + lr;

  __shared__ alignas(16) bf16 Ks[2][4096];
  __shared__ alignas(16) bf16 Vs[2][4096];
  __shared__ alignas(16) bf16 Ps[4][16 * 72];   // kept allocated for equal occupancy
  bf16* ps = &Ps[w][0];
  ps[lane] = (bf16)0.f;                          // keep allocation live

  const size_t hb = (size_t)bh << 17;
  const int b = bh >> 4, h = bh & 15;
  const f32x4 zero = {0.f, 0.f, 0.f, 0.f};
  const bf16* kbase = k_ws + hb;
  const bf16* vbase = vt_ws + hb;
  const size_t qtb = hb + ((size_t)qt << 12);

  bf16x8 aq[2];
#pragma unroll
  for (int c2 = 0; c2 < 2; ++c2)
    aq[c2] = load8(q_ws + qtb + (size_t)(((c2 * 4 + w) * 64 + fo) << 3));

  f32x4 o_acc[4];
#pragma unroll
  for (int j = 0; j < 4; ++j) o_acc[j] = zero;
  float lsum[4] = {0.f, 0.f, 0.f, 0.f};

  const int nt = qt + 1;
  auto ktof = [&](int s) { return (s == 0) ? qt : (s - 1); };

  auto stage = [&](int buf, int s) {
    const int kt = ktof(s);
    const bf16* kg = kbase + ((size_t)kt << 12);
    const bf16* vg = vbase + ((size_t)kt << 12);
#pragma unroll
    for (int it = 0; it < 2; ++it) {
      const int lin = it * 256 + tid;
      async_load16(kg + lin * 8, &Ks[buf][0] + lin * 8);
      async_load16(vg + lin * 8, &Vs[buf][0] + lin * 8);
    }
  };

  auto step = [&](int buf, bool diag) {
    const bf16* ks = &Ks[buf][0];
    const bf16* vs = &Vs[buf][0];
    f32x4 s[4];
    __builtin_amdgcn_s_setprio(1);
#pragma unroll
    for (int j = 0; j < 4; ++j) {
      s[j] = __builtin_amdgcn_mfma_f32_16x16x32_bf16(
          aq[0], load8(ks + (size_t)(((0 * 4 + j) * 64 + fo) << 3)), zero, 0, 0, 0);
      s[j] = __builtin_amdgcn_mfma_f32_16x16x32_bf16(
          aq[1], load8(ks + (size_t)(((1 * 4 + j) * 64 + fo) << 3)), s[j], 0, 0, 0);
    }
    __builtin_amdgcn_s_setprio(0);
    float p[4][4];
#pragma unroll
    for (int j = 0; j < 4; ++j) {
#pragma unroll
      for (int r = 0; r < 4; ++r) {
        float v = s[j][r];
        if (diag && (j * 16 + lr) > (w * 16 + lg * 4 + r)) v = NEG_BIG;
        p[j][r] = fexp2(v);
      }
    }
#pragma unroll
    for (int r = 0; r < 4; ++r)
      lsum[r] += (p[0][r] + p[1][r]) + (p[2][r] + p[3][r]);
    // NO ps writes, NO ps readback
    __builtin_amdgcn_s_setprio(1);
#pragma unroll
    for (int c2 = 0; c2 < 2; ++c2) {
      const bf16x8 ap = aq[c2];   // garbage operand, keeps PV dataflow intact
#pragma unroll
      for (int j = 0; j < 4; ++j)
        o_acc[j] = __builtin_amdgcn_mfma_f32_16x16x32_bf16(
            ap, load8(vs + (size_t)(((c2 * 4 + j) * 64 + fo) << 3)), o_acc[j], 0, 0, 0);
    }
    __builtin_amdgcn_s_setprio(0);
  };

  stage(0, 0);
  int cur = 0;
  for (int t = 0; t < nt; ++t) {
    asm volatile("s_waitcnt vmcnt(0)" ::: "memory");
    __builtin_amdgcn_s_barrier();
    if (t + 1 < nt) stage(cur ^ 1, t + 1);
    step(cur, t == 0);
    cur ^= 1;
  }

#pragma unroll
  for (int r = 0; r < 4; ++r) {
    float v = lsum[r];
#pragma unroll
    for (int off = 1; off < 16; off <<= 1) v += __shfl_xor(v, off, 64);
    const float inv = 1.f / v;
    const int t = qt * 64 + w * 16 + lg * 4 + r;
#pragma unroll
    for (int j = 0; j < 4; ++j) {
      const size_t idx = (((size_t)(b * 2048 + t)) << 10) | (size_t)(h * 64 + j * 16 + lr);
      a_ws[idx] = (bf16)(o_acc[j][r] * inv);
    }
  }
}

// DIAG 2: identical to attn v8 but NO softmax VALU (p = raw s, no exp/mask).
// P round-trip kept. Isolates the exp/mask VALU cost. Scratch out.
__global__ __launch_bounds__(256, 3) void attn_diag_noSM(
    const bf16* __restrict__ q_ws, const bf16* __restrict__ k_ws,
    const bf16* __restrict__ vt_ws, bf16* __restrict__ a_ws) {
  const int L = blockIdx.x;
  const int bh = (L & 7) * 4 + ((L >> 3) & 3);
  const int qt = 31 - (L >> 5);
  const int tid = threadIdx.x;
  const int lane = tid & 63, w = tid >> 6;
  const int lr = lane & 15, lg = lane >> 4;
  const int fo = lg * 16 + lr;

  __shared__ alignas(16) bf16 Ks[2][4096];
  __shared__ alignas(16) bf16 Vs[2][4096];
  __shared__ alignas(16) bf16 Ps[4][16 * 72];
  bf16* ps = &Ps[w][0];

  const size_t hb = (size_t)bh << 17;
  const int b = bh >> 4, h = bh & 15;
  const f32x4 zero = {0.f, 0.f, 0.f, 0.f};
  const bf16* kbase = k_ws + hb;
  const bf16* vbase = vt_ws + hb;
  const size_t qtb = hb + ((size_t)qt << 12);

  bf16x8 aq[2];
#pragma unroll
  for (int c2 = 0; c2 < 2; ++c2)
    aq[c2] = load8(q_ws + qtb + (size_t)(((c2 * 4 + w) * 64 + fo) << 3));

  f32x4 o_acc[4];
#pragma unroll
  for (int j = 0; j < 4; ++j) o_acc[j] = zero;
  float lsum[4] = {0.f, 0.f, 0.f, 0.f};

  const int nt = qt + 1;
  auto ktof = [&](int s) { return (s == 0) ? qt : (s - 1); };

  auto stage = [&](int buf, int s) {
    const int kt = ktof(s);
    const bf16* kg = kbase + ((size_t)kt << 12);
    const bf16* vg = vbase + ((size_t)kt << 12);
#pragma unroll
    for (int it = 0; it < 2; ++it) {
      const int lin = it * 256 + tid;
      async_load16(kg + lin * 8, &Ks[buf][0] + lin * 8);
      async_load16(vg + lin * 8, &Vs[buf][0] + lin * 8);
    }
  };

  auto step = [&](int buf, bool diag) {
    (void)diag;
    const bf16* ks = &Ks[buf][0];
    const bf16* vs = &Vs[buf][0];
    f32x4 s[4];
    __builtin_amdgcn_s_setprio(1);
#pragma unroll
    for (int j = 0; j < 4; ++j) {
      s[j] = __builtin_amdgcn_mfma_f32_16x16x32_bf16(
          aq[0], load8(ks + (size_t)(((0 * 4 + j) * 64 + fo) << 3)), zero, 0, 0, 0);
      s[j] = __builtin_amdgcn_mfma_f32_16x16x32_bf16(
          aq[1], load8(ks + (size_t)(((1 * 4 + j) * 64 + fo) << 3)), s[j], 0, 0, 0);
    }
    __builtin_amdgcn_s_setprio(0);
    float p[4][4];
#pragma unroll
    for (int j = 0; j < 4; ++j)
#pragma unroll
      for (int r = 0; r < 4; ++r)
        p[j][r] = s[j][r];               // NO exp, NO mask
#pragma unroll
    for (int r = 0; r < 4; ++r)
      lsum[r] += (p[0][r] + p[1][r]) + (p[2][r] + p[3][r]);
#pragma unroll
    for (int j = 0; j < 4; ++j)
#pragma unroll
      for (int r = 0; r < 4; ++r)
        ps[(lg * 4 + r) * 72 + j * 16 + lr] = (bf16)p[j][r];
    __builtin_amdgcn_s_setprio(1);
#pragma unroll
    for (int c2 = 0; c2 < 2; ++c2) {
      const bf16x8 ap = load8(ps + lr * 72 + c2 * 32 + lg * 8);
#pragma unroll
      for (int j = 0; j < 4; ++j)
        o_acc[j] = __builtin_amdgcn_mfma_f32_16x16x32_bf16(
            ap, load8(vs + (size_t)(((c2 * 4 + j) * 64 + fo) << 3)), o_acc[j], 0, 0, 0);
    }
    __builtin_amdgcn_s_setprio(0);
  };

  stage(0, 0);
  int cur = 0;
  for (int t = 0; t < nt; ++t) {
    asm volatile("s_waitcnt vmcnt(0)" ::: "memory");
    __builtin_amdgcn_s_barrier();
    if (t + 1 < nt) stage(cur ^ 1, t + 1);
    step(cur, t == 0);
    cur ^= 1;
  }

#pragma unroll
  for (int r = 0; r < 4; ++r) {
    float v = lsum[r];
#pragma unroll
    for (int off = 1; off < 16; off <<= 1) v += __shfl_xor(v, off, 64);
    const float inv = 1.f / v;
    const int t = qt * 64 + w * 16 + lg * 4 + r;
#pragma unroll
    for (int j = 0; j < 4; ++j) {
      const size_t idx = (((size_t)(b * 2048 + t)) << 10) | (size_t)(h * 64 + j * 16 + lr);
      a_ws[idx] = (bf16)(o_acc[j][r] * inv);
    }
  }
}

// out_proj: grid 512 (was 256 = 1 block/CU, zero overlap). 128x64 tiles.
__global__ __launch_bounds__(256) void out_proj_kernel(
    const bf16* __restrict__ A, const bf16* __restrict__ Wp,
    const bf16* __restrict__ bp, void* __restrict__ out,
    const unsigned short* __restrict__ xraw) {
  const int L = blockIdx.x;
  const int xcd = L & 7;
  const int i2 = L >> 3;                 // 0..63
  const int m0 = (xcd * 4 + (i2 & 3)) << 7;
  const int n0 = (i2 >> 2) << 6;
  f32x4 acc[4][2];
  gemm_core_128x64_p(A, Wp, 1024, m0, n0, acc);

  const int tid = threadIdx.x;
  const int lane = tid & 63, wid = tid >> 6;
  const int wm = (wid >> 1) << 6, wn = (wid & 1) << 5;
  const int lr = lane & 15, lg = lane >> 4;
  const int isbf = sniff_bf16(xraw);
#pragma unroll
  for (int i = 0; i < 4; ++i) {
#pragma unroll
    for (int r = 0; r < 4; ++r) {
      const int m = m0 + wm + i * 16 + lg * 4 + r;
#pragma unroll
      for (int j = 0; j < 2; ++j) {
        const int n = n0 + wn + j * 16 + lr;
        const float v = acc[i][j][r] + (float)bp[n];
        const size_t idx = ((size_t)m << 10) | (size_t)n;
        if (isbf) ((bf16*)out)[idx] = (bf16)v;
        else      ((float*)out)[idx] = v;
      }
    }
  }
}

extern "C" void kernel_launch(void* const* d_in, const int* in_sizes, int n_in,
                              void* d_out, int out_size, void* d_ws, size_t ws_size,
                              hipStream_t stream) {
  (void)in_sizes; (void)n_in; (void)out_size;
  if (ws_size < (50u << 20)) return;

  char* ws = (char*)d_ws;
  bf16* q_ws  = (bf16*)(ws);                        // 8 MiB frag-order Q (pre-scaled)
  bf16* k_ws  = (bf16*)(ws + (8u << 20));           // 8 MiB frag-order K
  bf16* vt_ws = (bf16*)(ws + (16u << 20));          // 8 MiB frag-order V^T
  bf16* a_ws  = (bf16*)(ws + (24u << 20));          // 8 MiB row-major attn out
  bf16* xc    = (bf16*)(ws + (32u << 20));          // 8 MiB canonical x (diag scratch after qkv)
  bf16* Wqc   = (bf16*)(ws + (40u << 20));          // 2 MiB each
  bf16* Wkc   = (bf16*)(ws + (42u << 20));
  bf16* Wvc   = (bf16*)(ws + (44u << 20));
  bf16* Wpc   = (bf16*)(ws + (46u << 20));
  bf16* bpc   = (bf16*)(ws + (48u << 20));

  ConvArgs ca;
  ca.src[0] = d_in[0]; ca.dst[0] = xc;  ca.n[0] = 4096 * 1024;
  ca.src[1] = d_in[1]; ca.dst[1] = Wqc; ca.n[1] = 1024 * 1024;
  ca.src[2] = d_in[2]; ca.dst[2] = Wkc; ca.n[2] = 1024 * 1024;
  ca.src[3] = d_in[3]; ca.dst[3] = Wvc; ca.n[3] = 1024 * 1024;
  ca.src[4] = d_in[4]; ca.dst[4] = Wpc; ca.n[4] = 1024 * 1024;
  ca.src[5] = d_in[5]; ca.dst[5] = bpc; ca.n[5] = 1024;
  convert_kernel<<<dim3(512, 6), 256, 0, stream>>>(ca);

  qkv_proj_kernel<<<768, 256, 0, stream>>>(xc, Wqc, Wkc, Wvc, q_ws, k_ws, vt_ws);
  attn_kernel<<<1024, 256, 0, stream>>>(q_ws, k_ws, vt_ws, a_ws);
  out_proj_kernel<<<512, 256, 0, stream>>>(a_ws, Wpc, bpc, d_out,
                                           (const unsigned short*)d_in[0]);
  // ---- diagnostics (dead scratch output; deleted next round) ----
  attn_diag_noP <<<1024, 256, 0, stream>>>(q_ws, k_ws, vt_ws, xc);
  attn_diag_noSM<<<1024, 256, 0, stream>>>(q_ws, k_ws, vt_ws, xc);
}

// Round 8
// 200.735 us; speedup vs baseline: 1.2203x; 1.2203x over previous
//
#include <hip/hip_runtime.h>

typedef __bf16 bf16;
typedef __bf16 bf16x8 __attribute__((ext_vector_type(8)));
typedef float f32x4 __attribute__((ext_vector_type(4)));

typedef __attribute__((address_space(1))) const void as1_void;
typedef __attribute__((address_space(3))) void as3_void;

#define DEV __device__ __forceinline__
#define NEG_BIG (-1.0e30f)

// B=2, T=2048, C=1024, H=16, D=64; M = B*T = 4096

DEV void async_load16(const void* g, void* l) {
  __builtin_amdgcn_global_load_lds((as1_void*)g, (as3_void*)l, 16, 0, 0);
}
DEV bf16x8 load8(const bf16* p) { bf16x8 v; __builtin_memcpy(&v, p, 16); return v; }
DEV void store8(bf16* p, bf16x8 v) { __builtin_memcpy(p, &v, 16); }
// raw v_exp_f32 (2^x). Non-volatile asm: schedulable, kept live by use.
DEV float fexp2(float x) { float r; asm("v_exp_f32 %0, %1" : "=v"(r) : "v"(x)); return r; }

// ---------------- in-kernel dtype sniff (block-uniform, deterministic) ----------------
DEV int sniff_bf16(const unsigned short* __restrict__ xr) {
  const int lane = threadIdx.x & 63;
  const unsigned short w = xr[lane * 2];
  const int e = (w >> 7) & 0xFF;
  const bool sane = ((w & 0x7FFF) == 0) || (e >= 97 && e <= 157);
  return __popcll(__ballot(sane)) >= 48;
}

// ---------------- input canonicalization (-> bf16, row-major) ----------------
struct ConvArgs {
  const void* src[6];
  bf16* dst[6];
  int n[6];
};

__global__ __launch_bounds__(256) void convert_kernel(ConvArgs a) {
  const int isbf = sniff_bf16((const unsigned short*)a.src[0]);
  const int t = blockIdx.y;
  const int n = a.n[t];
  bf16* d = a.dst[t];
  const int stride = gridDim.x * 256 * 8;
  if (isbf) {
    const bf16* s = (const bf16*)a.src[t];
    for (int i = (blockIdx.x * 256 + threadIdx.x) * 8; i < n; i += stride)
      store8(d + i, load8(s + i));
  } else {
    const float* s = (const float*)a.src[t];
    for (int i = (blockIdx.x * 256 + threadIdx.x) * 8; i < n; i += stride) {
      float tmp[8];
      __builtin_memcpy(tmp, s + i, 32);
      bf16x8 v;
#pragma unroll
      for (int j = 0; j < 8; ++j) v[j] = (bf16)tmp[j];
      store8(d + i, v);
    }
  }
}

// ---------------- qkv GEMM core v4: A direct global->VGPR, B LDS-pipelined ---------
// Rationale (r7 PMC): qkv was the slowest kernel (43 us) with every pipe <=27%
// busy; the largest reducible term is the LDS unit (A staging-write + 4 of 8
// ds_read_b128 per wave-step are pure overhead, since the A-fragment of a
// row-major matrix is already a contiguous 16B at (row)*K + k0 + lg*8 -- the
// r2 load pattern, correct there, slow only because BOTH operands were
// latency-serial). Here: A-frags global->reg with 2-set ping-pong, prefetch
// distance 2 (~2 iterations ~ >500cy in flight, covers L2); B stays on the
// verified 3-buffer / 1-barrier / counted-vmcnt pipeline.
// vmcnt(6) at iteration top = leave {B(t+1) 2 gll + A(t+1) 4 loads} in
// flight; forces B(t)+A(t) complete. Safe under intra-iteration compiler
// reordering (hoisting B's gll earlier only makes the wait stricter); af
// register deps are additionally tracked by the compiler's own waitcnts.
DEV void gemm_core_128_ad(const bf16* A, const bf16* W, const int K, int m0, int n0,
                          f32x4 (&acc)[4][4]) {
  __shared__ alignas(16) bf16 Bs[3][128 * 32];
  const int tid = threadIdx.x;
  const int lane = tid & 63;
  const int wid = tid >> 6;
  const int wm = (wid >> 1) << 6;
  const int wn = (wid & 1) << 6;
  const int lr = lane & 15;
  const int lg = lane >> 4;

  // B staging offsets (2 chunks/thread), row-pair swizzled layout (verified r3)
  size_t srcB[2];
  int ldsoff[2];
#pragma unroll
  for (int it = 0; it < 2; ++it) {
    const int lin = it * 256 + tid;        // 16B chunk id, 0..511
    const int lr2 = lin >> 3, c = lin & 7;
    const int u = c ^ (lr2 & 7);
    const int r = lr2 * 2 + (u >> 2);      // source row 0..127
    const int g = u & 3;                   // source k-group (8 elems)
    srcB[it] = (size_t)(n0 + r) * K + (size_t)(g * 8);
    ldsoff[it] = lin * 8;
  }
  // B fragment read offsets
  int offB[4];
#pragma unroll
  for (int j = 0; j < 4; ++j) {
    const int r = wn + j * 16 + lr;
    const int cc = (lg | ((r & 1) << 2)) ^ ((r >> 1) & 7);
    offB[j] = (((r >> 1) << 3) | cc) * 8;
  }
  // A row pointers (fragment-shaped direct loads)
  const bf16* pa[4];
#pragma unroll
  for (int i = 0; i < 4; ++i)
    pa[i] = A + (size_t)(m0 + wm + i * 16 + lr) * K + (size_t)(lg * 8);

  const f32x4 zero = {0.f, 0.f, 0.f, 0.f};
#pragma unroll
  for (int i = 0; i < 4; ++i)
#pragma unroll
    for (int j = 0; j < 4; ++j) acc[i][j] = zero;

  const int nt = K >> 5;  // 32 (even)

  auto stageB = [&](int buf, int t) {
    const size_t k0 = (size_t)(t << 5);
#pragma unroll
    for (int it = 0; it < 2; ++it)
      async_load16(W + srcB[it] + k0, &Bs[buf][0] + ldsoff[it]);
  };
  auto loadA = [&](bf16x8 (&af)[4], int t) {
    const int k0 = t << 5;
#pragma unroll
    for (int i = 0; i < 4; ++i) af[i] = load8(pa[i] + k0);
  };
  auto compute = [&](int buf, const bf16x8 (&af)[4]) {
    const bf16* bs = &Bs[buf][0];
    bf16x8 bfr[4];
#pragma unroll
    for (int j = 0; j < 4; ++j) bfr[j] = load8(bs + offB[j]);
    __builtin_amdgcn_s_setprio(1);
#pragma unroll
    for (int i = 0; i < 4; ++i)
#pragma unroll
      for (int j = 0; j < 4; ++j)
        acc[i][j] = __builtin_amdgcn_mfma_f32_16x16x32_bf16(af[i], bfr[j], acc[i][j], 0, 0, 0);
    __builtin_amdgcn_s_setprio(0);
  };

  bf16x8 afA[4], afB[4];
  // prologue: tiles 0,1 in flight (B staged, A in regs)
  stageB(0, 0);
  loadA(afA, 0);
  stageB(1, 1);
  loadA(afB, 1);
  int b0 = 0, b1 = 1, b2 = 2;
  for (int t = 0; t < nt; t += 2) {
    // even sub-iteration: consume afA, buffer b0
    if (t + 1 < nt) asm volatile("s_waitcnt vmcnt(6)" ::: "memory");
    else            asm volatile("s_waitcnt vmcnt(0)" ::: "memory");
    __builtin_amdgcn_s_barrier();          // B tile t resident for all waves
    if (t + 2 < nt) stageB(b2, t + 2);     // buffer last read at iter t-1: safe
    compute(b0, afA);
    if (t + 2 < nt) loadA(afA, t + 2);     // refill consumed A set
    { const int tmp = b0; b0 = b1; b1 = b2; b2 = tmp; }
    // odd sub-iteration: consume afB (t+1 < nt always; nt even)
    if (t + 2 < nt) asm volatile("s_waitcnt vmcnt(6)" ::: "memory");
    else            asm volatile("s_waitcnt vmcnt(0)" ::: "memory");
    __builtin_amdgcn_s_barrier();
    if (t + 3 < nt) stageB(b2, t + 3);
    compute(b0, afB);
    if (t + 3 < nt) loadA(afB, t + 3);
    { const int tmp = b0; b0 = b1; b1 = b2; b2 = tmp; }
  }
}

// ---------------- GEMM core: 128x64 tile (out_proj, grid 512) -- unchanged r7 ------
DEV void gemm_core_128x64_p(const bf16* A, const bf16* W, const int K, int m0, int n0,
                            f32x4 (&acc)[4][2]) {
  __shared__ alignas(16) bf16 As[3][128 * 32];
  __shared__ alignas(16) bf16 Bs[3][64 * 32];
  const int tid = threadIdx.x;
  const int lane = tid & 63;
  const int wid = tid >> 6;
  const int wm = (wid >> 1) << 6;
  const int wn = (wid & 1) << 5;
  const int lr = lane & 15;
  const int lg = lane >> 4;

  size_t srcA[2], srcB;
  int ldsoffA[2], ldsoffB;
#pragma unroll
  for (int it = 0; it < 2; ++it) {
    const int lin = it * 256 + tid;        // A: 512 chunks
    const int lr2 = lin >> 3, c = lin & 7;
    const int u = c ^ (lr2 & 7);
    srcA[it] = (size_t)(m0 + lr2 * 2 + (u >> 2)) * K + (size_t)((u & 3) * 8);
    ldsoffA[it] = lin * 8;
  }
  {
    const int lin = tid;                   // B: 256 chunks (64 rows)
    const int lr2 = lin >> 3, c = lin & 7;
    const int u = c ^ (lr2 & 7);
    srcB = (size_t)(n0 + lr2 * 2 + (u >> 2)) * K + (size_t)((u & 3) * 8);
    ldsoffB = lin * 8;
  }
  int offA[4], offB[2];
#pragma unroll
  for (int i = 0; i < 4; ++i) {
    const int r = wm + i * 16 + lr;
    const int cc = (lg | ((r & 1) << 2)) ^ ((r >> 1) & 7);
    offA[i] = (((r >> 1) << 3) | cc) * 8;
  }
#pragma unroll
  for (int j = 0; j < 2; ++j) {
    const int r = wn + j * 16 + lr;
    const int cc = (lg | ((r & 1) << 2)) ^ ((r >> 1) & 7);
    offB[j] = (((r >> 1) << 3) | cc) * 8;
  }

  const f32x4 zero = {0.f, 0.f, 0.f, 0.f};
#pragma unroll
  for (int i = 0; i < 4; ++i)
#pragma unroll
    for (int j = 0; j < 2; ++j) acc[i][j] = zero;

  const int nt = K >> 5;  // 32

  auto stage = [&](int buf, int t) {
    const size_t k0 = (size_t)(t << 5);
#pragma unroll
    for (int it = 0; it < 2; ++it)
      async_load16(A + srcA[it] + k0, &As[buf][0] + ldsoffA[it]);
    async_load16(W + srcB + k0, &Bs[buf][0] + ldsoffB);
  };

  auto compute = [&](int buf) {
    const bf16* as = &As[buf][0];
    const bf16* bs = &Bs[buf][0];
    bf16x8 af[4], bfr[2];
#pragma unroll
    for (int i = 0; i < 4; ++i) af[i] = load8(as + offA[i]);
#pragma unroll
    for (int j = 0; j < 2; ++j) bfr[j] = load8(bs + offB[j]);
    __builtin_amdgcn_s_setprio(1);
#pragma unroll
    for (int i = 0; i < 4; ++i)
#pragma unroll
      for (int j = 0; j < 2; ++j)
        acc[i][j] = __builtin_amdgcn_mfma_f32_16x16x32_bf16(af[i], bfr[j], acc[i][j], 0, 0, 0);
    __builtin_amdgcn_s_setprio(0);
  };

  stage(0, 0);
  stage(1, 1);
  int b0 = 0, b1 = 1, b2 = 2;
  for (int t = 0; t < nt; ++t) {
    if (t + 1 < nt) asm volatile("s_waitcnt vmcnt(3)" ::: "memory");
    else            asm volatile("s_waitcnt vmcnt(0)" ::: "memory");
    __builtin_amdgcn_s_barrier();
    if (t + 2 < nt) stage(b2, t + 2);
    compute(b0);
    const int tmp = b0; b0 = b1; b1 = b2; b2 = tmp;
  }
}

// Fragment-order address for a 64x64 tile, element (row, col):
DEV size_t frag_idx(int row, int col) {
  return ((size_t)(((col >> 5) * 4 + ((row >> 4) & 3)) * 64 + ((col >> 3) & 3) * 16 + (row & 15)) << 3)
         | (size_t)(col & 7);
}

// 1-D grid 768. Q pre-scaled by 0.125*log2(e) so attn uses raw v_exp_f32.
__global__ __launch_bounds__(256, 3) void qkv_proj_kernel(
    const bf16* __restrict__ x, const bf16* __restrict__ Wq,
    const bf16* __restrict__ Wk, const bf16* __restrict__ Wv,
    bf16* __restrict__ q_ws, bf16* __restrict__ k_ws, bf16* __restrict__ vt_ws) {
  const int L = blockIdx.x;
  const int xcd = L & 7;
  const int i2 = L >> 3;                 // 0..95
  const int m0 = (xcd * 4 + (i2 & 3)) << 7;
  const int rest = i2 >> 2;              // 0..23
  const int n0 = (rest & 7) << 7;
  const int mode = rest >> 3;            // 0..2
  const bf16* W = (mode == 0) ? Wq : (mode == 1) ? Wk : Wv;
  f32x4 acc[4][4];
  gemm_core_128_ad(x, W, 1024, m0, n0, acc);

  const int tid = threadIdx.x;
  const int lane = tid & 63, wid = tid >> 6;
  const int wm = (wid >> 1) << 6, wn = (wid & 1) << 6;
  const int lr = lane & 15, lg = lane >> 4;
  bf16* out = (mode == 0) ? q_ws : (mode == 1) ? k_ws : vt_ws;
  const float scale = (mode == 0) ? 0.18033688011112042f : 1.0f;  // 0.125*log2e
#pragma unroll
  for (int i = 0; i < 4; ++i) {
#pragma unroll
    for (int r = 0; r < 4; ++r) {
      const int m = m0 + wm + i * 16 + lg * 4 + r;
      const int b = m >> 11, t = m & 2047;
#pragma unroll
      for (int j = 0; j < 4; ++j) {
        const int n = n0 + wn + j * 16 + lr;
        const int h = n >> 6, d = n & 63;
        const float v = acc[i][j][r] * scale;
        const size_t base = ((size_t)(b * 16 + h) << 17) + ((size_t)(t >> 6) << 12);
        const size_t idx = base + ((mode < 2) ? frag_idx(t & 63, d) : frag_idx(d, t & 63));
        out[idx] = (bf16)v;
      }
    }
  }
}

// Flash attention v8 (unchanged r7: 2 K/V buffers, 3 blocks/CU, exp2).
__global__ __launch_bounds__(256, 3) void attn_kernel(
    const bf16* __restrict__ q_ws, const bf16* __restrict__ k_ws,
    const bf16* __restrict__ vt_ws, bf16* __restrict__ a_ws) {
  const int L = blockIdx.x;
  const int bh = (L & 7) * 4 + ((L >> 3) & 3);
  const int qt = 31 - (L >> 5);
  const int tid = threadIdx.x;
  const int lane = tid & 63, w = tid >> 6;
  const int lr = lane & 15, lg = lane >> 4;
  const int fo = lg * 16 + lr;

  __shared__ alignas(16) bf16 Ks[2][4096];
  __shared__ alignas(16) bf16 Vs[2][4096];
  __shared__ alignas(16) bf16 Ps[4][16 * 72];
  bf16* ps = &Ps[w][0];

  const size_t hb = (size_t)bh << 17;
  const int b = bh >> 4, h = bh & 15;
  const f32x4 zero = {0.f, 0.f, 0.f, 0.f};
  const bf16* kbase = k_ws + hb;
  const bf16* vbase = vt_ws + hb;
  const size_t qtb = hb + ((size_t)qt << 12);

  bf16x8 aq[2];
#pragma unroll
  for (int c2 = 0; c2 < 2; ++c2)
    aq[c2] = load8(q_ws + qtb + (size_t)(((c2 * 4 + w) * 64 + fo) << 3));

  f32x4 o_acc[4];
#pragma unroll
  for (int j = 0; j < 4; ++j) o_acc[j] = zero;
  float lsum[4] = {0.f, 0.f, 0.f, 0.f};

  const int nt = qt + 1;
  auto ktof = [&](int s) { return (s == 0) ? qt : (s - 1); };

  auto stage = [&](int buf, int s) {
    const int kt = ktof(s);
    const bf16* kg = kbase + ((size_t)kt << 12);
    const bf16* vg = vbase + ((size_t)kt << 12);
#pragma unroll
    for (int it = 0; it < 2; ++it) {
      const int lin = it * 256 + tid;
      async_load16(kg + lin * 8, &Ks[buf][0] + lin * 8);
      async_load16(vg + lin * 8, &Vs[buf][0] + lin * 8);
    }
  };

  auto step = [&](int buf, bool diag) {
    const bf16* ks = &Ks[buf][0];
    const bf16* vs = &Vs[buf][0];
    f32x4 s[4];
    __builtin_amdgcn_s_setprio(1);
#pragma unroll
    for (int j = 0; j < 4; ++j) {
      s[j] = __builtin_amdgcn_mfma_f32_16x16x32_bf16(
          aq[0], load8(ks + (size_t)(((0 * 4 + j) * 64 + fo) << 3)), zero, 0, 0, 0);
      s[j] = __builtin_amdgcn_mfma_f32_16x16x32_bf16(
          aq[1], load8(ks + (size_t)(((1 * 4 + j) * 64 + fo) << 3)), s[j], 0, 0, 0);
    }
    __builtin_amdgcn_s_setprio(0);
    float p[4][4];
#pragma unroll
    for (int j = 0; j < 4; ++j) {
#pragma unroll
      for (int r = 0; r < 4; ++r) {
        float v = s[j][r];
        if (diag && (j * 16 + lr) > (w * 16 + lg * 4 + r)) v = NEG_BIG;
        p[j][r] = fexp2(v);
      }
    }
#pragma unroll
    for (int r = 0; r < 4; ++r)
      lsum[r] += (p[0][r] + p[1][r]) + (p[2][r] + p[3][r]);
#pragma unroll
    for (int j = 0; j < 4; ++j)
#pragma unroll
      for (int r = 0; r < 4; ++r)
        ps[(lg * 4 + r) * 72 + j * 16 + lr] = (bf16)p[j][r];
    __builtin_amdgcn_s_setprio(1);
#pragma unroll
    for (int c2 = 0; c2 < 2; ++c2) {
      const bf16x8 ap = load8(ps + lr * 72 + c2 * 32 + lg * 8);
#pragma unroll
      for (int j = 0; j < 4; ++j)
        o_acc[j] = __builtin_amdgcn_mfma_f32_16x16x32_bf16(
            ap, load8(vs + (size_t)(((c2 * 4 + j) * 64 + fo) << 3)), o_acc[j], 0, 0, 0);
    }
    __builtin_amdgcn_s_setprio(0);
  };

  stage(0, 0);
  int cur = 0;
  for (int t = 0; t < nt; ++t) {
    asm volatile("s_waitcnt vmcnt(0)" ::: "memory");
    __builtin_amdgcn_s_barrier();
    if (t + 1 < nt) stage(cur ^ 1, t + 1);
    step(cur, t == 0);
    cur ^= 1;
  }

#pragma unroll
  for (int r = 0; r < 4; ++r) {
    float v = lsum[r];
#pragma unroll
    for (int off = 1; off < 16; off <<= 1) v += __shfl_xor(v, off, 64);
    const float inv = 1.f / v;
    const int t = qt * 64 + w * 16 + lg * 4 + r;
#pragma unroll
    for (int j = 0; j < 4; ++j) {
      const size_t idx = (((size_t)(b * 2048 + t)) << 10) | (size_t)(h * 64 + j * 16 + lr);
      a_ws[idx] = (bf16)(o_acc[j][r] * inv);
    }
  }
}

// out_proj: grid 512, 128x64 tiles (unchanged r7).
__global__ __launch_bounds__(256) void out_proj_kernel(
    const bf16* __restrict__ A, const bf16* __restrict__ Wp,
    const bf16* __restrict__ bp, void* __restrict__ out,
    const unsigned short* __restrict__ xraw) {
  const int L = blockIdx.x;
  const int xcd = L & 7;
  const int i2 = L >> 3;                 // 0..63
  const int m0 = (xcd * 4 + (i2 & 3)) << 7;
  const int n0 = (i2 >> 2) << 6;
  f32x4 acc[4][2];
  gemm_core_128x64_p(A, Wp, 1024, m0, n0, acc);

  const int tid = threadIdx.x;
  const int lane = tid & 63, wid = tid >> 6;
  const int wm = (wid >> 1) << 6, wn = (wid & 1) << 5;
  const int lr = lane & 15, lg = lane >> 4;
  const int isbf = sniff_bf16(xraw);
#pragma unroll
  for (int i = 0; i < 4; ++i) {
#pragma unroll
    for (int r = 0; r < 4; ++r) {
      const int m = m0 + wm + i * 16 + lg * 4 + r;
#pragma unroll
      for (int j = 0; j < 2; ++j) {
        const int n = n0 + wn + j * 16 + lr;
        const float v = acc[i][j][r] + (float)bp[n];
        const size_t idx = ((size_t)m << 10) | (size_t)n;
        if (isbf) ((bf16*)out)[idx] = (bf16)v;
        else      ((float*)out)[idx] = v;
      }
    }
  }
}

extern "C" void kernel_launch(void* const* d_in, const int* in_sizes, int n_in,
                              void* d_out, int out_size, void* d_ws, size_t ws_size,
                              hipStream_t stream) {
  (void)in_sizes; (void)n_in; (void)out_size;
  if (ws_size < (50u << 20)) return;

  char* ws = (char*)d_ws;
  bf16* q_ws  = (bf16*)(ws);                        // 8 MiB frag-order Q (pre-scaled)
  bf16* k_ws  = (bf16*)(ws + (8u << 20));           // 8 MiB frag-order K
  bf16* vt_ws = (bf16*)(ws + (16u << 20));          // 8 MiB frag-order V^T
  bf16* a_ws  = (bf16*)(ws + (24u << 20));          // 8 MiB row-major attn out
  bf16* xc    = (bf16*)(ws + (32u << 20));          // 8 MiB canonical x
  bf16* Wqc   = (bf16*)(ws + (40u << 20));          // 2 MiB each
  bf16* Wkc   = (bf16*)(ws + (42u << 20));
  bf16* Wvc   = (bf16*)(ws + (44u << 20));
  bf16* Wpc   = (bf16*)(ws + (46u << 20));
  bf16* bpc   = (bf16*)(ws + (48u << 20));

  ConvArgs ca;
  ca.src[0] = d_in[0]; ca.dst[0] = xc;  ca.n[0] = 4096 * 1024;
  ca.src[1] = d_in[1]; ca.dst[1] = Wqc; ca.n[1] = 1024 * 1024;
  ca.src[2] = d_in[2]; ca.dst[2] = Wkc; ca.n[2] = 1024 * 1024;
  ca.src[3] = d_in[3]; ca.dst[3] = Wvc; ca.n[3] = 1024 * 1024;
  ca.src[4] = d_in[4]; ca.dst[4] = Wpc; ca.n[4] = 1024 * 1024;
  ca.src[5] = d_in[5]; ca.dst[5] = bpc; ca.n[5] = 1024;
  convert_kernel<<<dim3(512, 6), 256, 0, stream>>>(ca);

  qkv_proj_kernel<<<768, 256, 0, stream>>>(xc, Wqc, Wkc, Wvc, q_ws, k_ws, vt_ws);
  attn_kernel<<<1024, 256, 0, stream>>>(q_ws, k_ws, vt_ws, a_ws);
  out_proj_kernel<<<512, 256, 0, stream>>>(a_ws, Wpc, bpc, d_out,
                                           (const unsigned short*)d_in[0]);
}

// Round 9
// 178.491 us; speedup vs baseline: 1.3724x; 1.1246x over previous
//
#include <hip/hip_runtime.h>

typedef __bf16 bf16;
typedef __bf16 bf16x8 __attribute__((ext_vector_type(8)));
typedef float f32x4 __attribute__((ext_vector_type(4)));

typedef __attribute__((address_space(1))) const void as1_void;
typedef __attribute__((address_space(3))) void as3_void;

#define DEV __device__ __forceinline__
#define NEG_BIG (-1.0e30f)

// B=2, T=2048, C=1024, H=16, D=64; M = B*T = 4096

DEV void async_load16(const void* g, void* l) {
  __builtin_amdgcn_global_load_lds((as1_void*)g, (as3_void*)l, 16, 0, 0);
}
DEV bf16x8 load8(const bf16* p) { bf16x8 v; __builtin_memcpy(&v, p, 16); return v; }
DEV void store8(bf16* p, bf16x8 v) { __builtin_memcpy(p, &v, 16); }
// raw v_exp_f32 (2^x). Non-volatile asm: schedulable, kept live by use.
DEV float fexp2(float x) { float r; asm("v_exp_f32 %0, %1" : "=v"(r) : "v"(x)); return r; }

// ---------------- in-kernel dtype sniff (block-uniform, deterministic) ----------------
DEV int sniff_bf16(const unsigned short* __restrict__ xr) {
  const int lane = threadIdx.x & 63;
  const unsigned short w = xr[lane * 2];
  const int e = (w >> 7) & 0xFF;
  const bool sane = ((w & 0x7FFF) == 0) || (e >= 97 && e <= 157);
  return __popcll(__ballot(sane)) >= 48;
}

// ---------------- input canonicalization (-> bf16, row-major) ----------------
struct ConvArgs {
  const void* src[6];
  bf16* dst[6];
  int n[6];
};

__global__ __launch_bounds__(256) void convert_kernel(ConvArgs a) {
  const int isbf = sniff_bf16((const unsigned short*)a.src[0]);
  const int t = blockIdx.y;
  const int n = a.n[t];
  bf16* d = a.dst[t];
  const int stride = gridDim.x * 256 * 8;
  if (isbf) {
    const bf16* s = (const bf16*)a.src[t];
    for (int i = (blockIdx.x * 256 + threadIdx.x) * 8; i < n; i += stride)
      store8(d + i, load8(s + i));
  } else {
    const float* s = (const float*)a.src[t];
    for (int i = (blockIdx.x * 256 + threadIdx.x) * 8; i < n; i += stride) {
      float tmp[8];
      __builtin_memcpy(tmp, s + i, 32);
      bf16x8 v;
#pragma unroll
      for (int j = 0; j < 8; ++j) v[j] = (bf16)tmp[j];
      store8(d + i, v);
    }
  }
}

// ---------------- GEMM core v3: BK=32, 3 LDS buffers, 1 barrier/K-tile ----------------
// Verified r3/r7: qkv at 43 us, MfmaUtil 22%. r8's A-direct hybrid REGRESSED
// (66.8 us, VALUBusy 10%): A-register loads put full L2 latency as a register
// dep in front of the MFMA cluster; the staged gll->ds_read path absorbs it.
// Do not re-attempt register-direct operands in barrier-lockstep loops.
DEV void gemm_core_128_p(const bf16* A, const bf16* W, const int K, int m0, int n0,
                         f32x4 (&acc)[4][4]) {
  __shared__ alignas(16) bf16 As[3][128 * 32];
  __shared__ alignas(16) bf16 Bs[3][128 * 32];
  const int tid = threadIdx.x;
  const int lane = tid & 63;
  const int wid = tid >> 6;
  const int wm = (wid >> 1) << 6;
  const int wn = (wid & 1) << 6;
  const int lr = lane & 15;
  const int lg = lane >> 4;

  size_t srcA[2], srcB[2];
  int ldsoff[2];
#pragma unroll
  for (int it = 0; it < 2; ++it) {
    const int lin = it * 256 + tid;        // 16B chunk id, 0..511
    const int lr2 = lin >> 3, c = lin & 7;
    const int u = c ^ (lr2 & 7);
    const int r = lr2 * 2 + (u >> 2);      // source row 0..127
    const int g = u & 3;                   // source k-group (8 elems)
    srcA[it] = (size_t)(m0 + r) * K + (size_t)(g * 8);
    srcB[it] = (size_t)(n0 + r) * K + (size_t)(g * 8);
    ldsoff[it] = lin * 8;
  }
  int offA[4], offB[4];
#pragma unroll
  for (int i = 0; i < 4; ++i) {
    const int r = wm + i * 16 + lr;
    const int cc = (lg | ((r & 1) << 2)) ^ ((r >> 1) & 7);
    offA[i] = (((r >> 1) << 3) | cc) * 8;
  }
#pragma unroll
  for (int j = 0; j < 4; ++j) {
    const int r = wn + j * 16 + lr;
    const int cc = (lg | ((r & 1) << 2)) ^ ((r >> 1) & 7);
    offB[j] = (((r >> 1) << 3) | cc) * 8;
  }

  const f32x4 zero = {0.f, 0.f, 0.f, 0.f};
#pragma unroll
  for (int i = 0; i < 4; ++i)
#pragma unroll
    for (int j = 0; j < 4; ++j) acc[i][j] = zero;

  const int nt = K >> 5;  // 32

  auto stage = [&](int buf, int t) {
    const size_t k0 = (size_t)(t << 5);
#pragma unroll
    for (int it = 0; it < 2; ++it) {
      async_load16(A + srcA[it] + k0, &As[buf][0] + ldsoff[it]);
      async_load16(W + srcB[it] + k0, &Bs[buf][0] + ldsoff[it]);
    }
  };

  auto compute = [&](int buf) {
    const bf16* as = &As[buf][0];
    const bf16* bs = &Bs[buf][0];
    bf16x8 af[4], bfr[4];
#pragma unroll
    for (int i = 0; i < 4; ++i) af[i] = load8(as + offA[i]);
#pragma unroll
    for (int j = 0; j < 4; ++j) bfr[j] = load8(bs + offB[j]);
    __builtin_amdgcn_s_setprio(1);
#pragma unroll
    for (int i = 0; i < 4; ++i)
#pragma unroll
      for (int j = 0; j < 4; ++j)
        acc[i][j] = __builtin_amdgcn_mfma_f32_16x16x32_bf16(af[i], bfr[j], acc[i][j], 0, 0, 0);
    __builtin_amdgcn_s_setprio(0);
  };

  stage(0, 0);
  stage(1, 1);
  int b0 = 0, b1 = 1, b2 = 2;
  for (int t = 0; t < nt; ++t) {
    if (t + 1 < nt) asm volatile("s_waitcnt vmcnt(4)" ::: "memory");
    else            asm volatile("s_waitcnt vmcnt(0)" ::: "memory");
    __builtin_amdgcn_s_barrier();          // all waves' tile-t portions in LDS
    if (t + 2 < nt) stage(b2, t + 2);      // buffer last read at iter t-1: safe
    compute(b0);
    const int tmp = b0; b0 = b1; b1 = b2; b2 = tmp;
  }
}

// ---------------- GEMM core: 128x64 tile (out_proj, grid 512) -- verified r7 -------
DEV void gemm_core_128x64_p(const bf16* A, const bf16* W, const int K, int m0, int n0,
                            f32x4 (&acc)[4][2]) {
  __shared__ alignas(16) bf16 As[3][128 * 32];
  __shared__ alignas(16) bf16 Bs[3][64 * 32];
  const int tid = threadIdx.x;
  const int lane = tid & 63;
  const int wid = tid >> 6;
  const int wm = (wid >> 1) << 6;
  const int wn = (wid & 1) << 5;
  const int lr = lane & 15;
  const int lg = lane >> 4;

  size_t srcA[2], srcB;
  int ldsoffA[2], ldsoffB;
#pragma unroll
  for (int it = 0; it < 2; ++it) {
    const int lin = it * 256 + tid;        // A: 512 chunks
    const int lr2 = lin >> 3, c = lin & 7;
    const int u = c ^ (lr2 & 7);
    srcA[it] = (size_t)(m0 + lr2 * 2 + (u >> 2)) * K + (size_t)((u & 3) * 8);
    ldsoffA[it] = lin * 8;
  }
  {
    const int lin = tid;                   // B: 256 chunks (64 rows)
    const int lr2 = lin >> 3, c = lin & 7;
    const int u = c ^ (lr2 & 7);
    srcB = (size_t)(n0 + lr2 * 2 + (u >> 2)) * K + (size_t)((u & 3) * 8);
    ldsoffB = lin * 8;
  }
  int offA[4], offB[2];
#pragma unroll
  for (int i = 0; i < 4; ++i) {
    const int r = wm + i * 16 + lr;
    const int cc = (lg | ((r & 1) << 2)) ^ ((r >> 1) & 7);
    offA[i] = (((r >> 1) << 3) | cc) * 8;
  }
#pragma unroll
  for (int j = 0; j < 2; ++j) {
    const int r = wn + j * 16 + lr;
    const int cc = (lg | ((r & 1) << 2)) ^ ((r >> 1) & 7);
    offB[j] = (((r >> 1) << 3) | cc) * 8;
  }

  const f32x4 zero = {0.f, 0.f, 0.f, 0.f};
#pragma unroll
  for (int i = 0; i < 4; ++i)
#pragma unroll
    for (int j = 0; j < 2; ++j) acc[i][j] = zero;

  const int nt = K >> 5;  // 32

  auto stage = [&](int buf, int t) {
    const size_t k0 = (size_t)(t << 5);
#pragma unroll
    for (int it = 0; it < 2; ++it)
      async_load16(A + srcA[it] + k0, &As[buf][0] + ldsoffA[it]);
    async_load16(W + srcB + k0, &Bs[buf][0] + ldsoffB);
  };

  auto compute = [&](int buf) {
    const bf16* as = &As[buf][0];
    const bf16* bs = &Bs[buf][0];
    bf16x8 af[4], bfr[2];
#pragma unroll
    for (int i = 0; i < 4; ++i) af[i] = load8(as + offA[i]);
#pragma unroll
    for (int j = 0; j < 2; ++j) bfr[j] = load8(bs + offB[j]);
    __builtin_amdgcn_s_setprio(1);
#pragma unroll
    for (int i = 0; i < 4; ++i)
#pragma unroll
      for (int j = 0; j < 2; ++j)
        acc[i][j] = __builtin_amdgcn_mfma_f32_16x16x32_bf16(af[i], bfr[j], acc[i][j], 0, 0, 0);
    __builtin_amdgcn_s_setprio(0);
  };

  stage(0, 0);
  stage(1, 1);
  int b0 = 0, b1 = 1, b2 = 2;
  for (int t = 0; t < nt; ++t) {
    if (t + 1 < nt) asm volatile("s_waitcnt vmcnt(3)" ::: "memory");
    else            asm volatile("s_waitcnt vmcnt(0)" ::: "memory");
    __builtin_amdgcn_s_barrier();
    if (t + 2 < nt) stage(b2, t + 2);
    compute(b0);
    const int tmp = b0; b0 = b1; b1 = b2; b2 = tmp;
  }
}

// Fragment-order address for a 64x64 tile, element (row, col):
DEV size_t frag_idx(int row, int col) {
  return ((size_t)(((col >> 5) * 4 + ((row >> 4) & 3)) * 64 + ((col >> 3) & 3) * 16 + (row & 15)) << 3)
         | (size_t)(col & 7);
}

// 1-D grid 768. Q pre-scaled by 0.125*log2(e) so attn uses raw v_exp_f32.
__global__ __launch_bounds__(256) void qkv_proj_kernel(
    const bf16* __restrict__ x, const bf16* __restrict__ Wq,
    const bf16* __restrict__ Wk, const bf16* __restrict__ Wv,
    bf16* __restrict__ q_ws, bf16* __restrict__ k_ws, bf16* __restrict__ vt_ws) {
  const int L = blockIdx.x;
  const int xcd = L & 7;
  const int i2 = L >> 3;                 // 0..95
  const int m0 = (xcd * 4 + (i2 & 3)) << 7;
  const int rest = i2 >> 2;              // 0..23
  const int n0 = (rest & 7) << 7;
  const int mode = rest >> 3;            // 0..2
  const bf16* W = (mode == 0) ? Wq : (mode == 1) ? Wk : Wv;
  f32x4 acc[4][4];
  gemm_core_128_p(x, W, 1024, m0, n0, acc);

  const int tid = threadIdx.x;
  const int lane = tid & 63, wid = tid >> 6;
  const int wm = (wid >> 1) << 6, wn = (wid & 1) << 6;
  const int lr = lane & 15, lg = lane >> 4;
  bf16* out = (mode == 0) ? q_ws : (mode == 1) ? k_ws : vt_ws;
  const float scale = (mode == 0) ? 0.18033688011112042f : 1.0f;  // 0.125*log2e
#pragma unroll
  for (int i = 0; i < 4; ++i) {
#pragma unroll
    for (int r = 0; r < 4; ++r) {
      const int m = m0 + wm + i * 16 + lg * 4 + r;
      const int b = m >> 11, t = m & 2047;
#pragma unroll
      for (int j = 0; j < 4; ++j) {
        const int n = n0 + wn + j * 16 + lr;
        const int h = n >> 6, d = n & 63;
        const float v = acc[i][j][r] * scale;
        const size_t base = ((size_t)(b * 16 + h) << 17) + ((size_t)(t >> 6) << 12);
        const size_t idx = base + ((mode < 2) ? frag_idx(t & 63, d) : frag_idx(d, t & 63));
        out[idx] = (bf16)v;
      }
    }
  }
}

// Flash attention v8 (verified r7/r8: 2 K/V buffers, 3 blocks/CU, exp2).
__global__ __launch_bounds__(256, 3) void attn_kernel(
    const bf16* __restrict__ q_ws, const bf16* __restrict__ k_ws,
    const bf16* __restrict__ vt_ws, bf16* __restrict__ a_ws) {
  const int L = blockIdx.x;
  const int bh = (L & 7) * 4 + ((L >> 3) & 3);
  const int qt = 31 - (L >> 5);
  const int tid = threadIdx.x;
  const int lane = tid & 63, w = tid >> 6;
  const int lr = lane & 15, lg = lane >> 4;
  const int fo = lg * 16 + lr;

  __shared__ alignas(16) bf16 Ks[2][4096];
  __shared__ alignas(16) bf16 Vs[2][4096];
  __shared__ alignas(16) bf16 Ps[4][16 * 72];
  bf16* ps = &Ps[w][0];

  const size_t hb = (size_t)bh << 17;
  const int b = bh >> 4, h = bh & 15;
  const f32x4 zero = {0.f, 0.f, 0.f, 0.f};
  const bf16* kbase = k_ws + hb;
  const bf16* vbase = vt_ws + hb;
  const size_t qtb = hb + ((size_t)qt << 12);

  bf16x8 aq[2];
#pragma unroll
  for (int c2 = 0; c2 < 2; ++c2)
    aq[c2] = load8(q_ws + qtb + (size_t)(((c2 * 4 + w) * 64 + fo) << 3));

  f32x4 o_acc[4];
#pragma unroll
  for (int j = 0; j < 4; ++j) o_acc[j] = zero;
  float lsum[4] = {0.f, 0.f, 0.f, 0.f};

  const int nt = qt + 1;
  auto ktof = [&](int s) { return (s == 0) ? qt : (s - 1); };

  auto stage = [&](int buf, int s) {
    const int kt = ktof(s);
    const bf16* kg = kbase + ((size_t)kt << 12);
    const bf16* vg = vbase + ((size_t)kt << 12);
#pragma unroll
    for (int it = 0; it < 2; ++it) {
      const int lin = it * 256 + tid;
      async_load16(kg + lin * 8, &Ks[buf][0] + lin * 8);
      async_load16(vg + lin * 8, &Vs[buf][0] + lin * 8);
    }
  };

  auto step = [&](int buf, bool diag) {
    const bf16* ks = &Ks[buf][0];
    const bf16* vs = &Vs[buf][0];
    f32x4 s[4];
    __builtin_amdgcn_s_setprio(1);
#pragma unroll
    for (int j = 0; j < 4; ++j) {
      s[j] = __builtin_amdgcn_mfma_f32_16x16x32_bf16(
          aq[0], load8(ks + (size_t)(((0 * 4 + j) * 64 + fo) << 3)), zero, 0, 0, 0);
      s[j] = __builtin_amdgcn_mfma_f32_16x16x32_bf16(
          aq[1], load8(ks + (size_t)(((1 * 4 + j) * 64 + fo) << 3)), s[j], 0, 0, 0);
    }
    __builtin_amdgcn_s_setprio(0);
    float p[4][4];
#pragma unroll
    for (int j = 0; j < 4; ++j) {
#pragma unroll
      for (int r = 0; r < 4; ++r) {
        float v = s[j][r];
        if (diag && (j * 16 + lr) > (w * 16 + lg * 4 + r)) v = NEG_BIG;
        p[j][r] = fexp2(v);
      }
    }
#pragma unroll
    for (int r = 0; r < 4; ++r)
      lsum[r] += (p[0][r] + p[1][r]) + (p[2][r] + p[3][r]);
#pragma unroll
    for (int j = 0; j < 4; ++j)
#pragma unroll
      for (int r = 0; r < 4; ++r)
        ps[(lg * 4 + r) * 72 + j * 16 + lr] = (bf16)p[j][r];
    __builtin_amdgcn_s_setprio(1);
#pragma unroll
    for (int c2 = 0; c2 < 2; ++c2) {
      const bf16x8 ap = load8(ps + lr * 72 + c2 * 32 + lg * 8);
#pragma unroll
      for (int j = 0; j < 4; ++j)
        o_acc[j] = __builtin_amdgcn_mfma_f32_16x16x32_bf16(
            ap, load8(vs + (size_t)(((c2 * 4 + j) * 64 + fo) << 3)), o_acc[j], 0, 0, 0);
    }
    __builtin_amdgcn_s_setprio(0);
  };

  stage(0, 0);
  int cur = 0;
  for (int t = 0; t < nt; ++t) {
    asm volatile("s_waitcnt vmcnt(0)" ::: "memory");
    __builtin_amdgcn_s_barrier();
    if (t + 1 < nt) stage(cur ^ 1, t + 1);
    step(cur, t == 0);
    cur ^= 1;
  }

#pragma unroll
  for (int r = 0; r < 4; ++r) {
    float v = lsum[r];
#pragma unroll
    for (int off = 1; off < 16; off <<= 1) v += __shfl_xor(v, off, 64);
    const float inv = 1.f / v;
    const int t = qt * 64 + w * 16 + lg * 4 + r;
#pragma unroll
    for (int j = 0; j < 4; ++j) {
      const size_t idx = (((size_t)(b * 2048 + t)) << 10) | (size_t)(h * 64 + j * 16 + lr);
      a_ws[idx] = (bf16)(o_acc[j][r] * inv);
    }
  }
}

// out_proj: grid 512, 128x64 tiles (verified r7).
__global__ __launch_bounds__(256) void out_proj_kernel(
    const bf16* __restrict__ A, const bf16* __restrict__ Wp,
    const bf16* __restrict__ bp, void* __restrict__ out,
    const unsigned short* __restrict__ xraw) {
  const int L = blockIdx.x;
  const int xcd = L & 7;
  const int i2 = L >> 3;                 // 0..63
  const int m0 = (xcd * 4 + (i2 & 3)) << 7;
  const int n0 = (i2 >> 2) << 6;
  f32x4 acc[4][2];
  gemm_core_128x64_p(A, Wp, 1024, m0, n0, acc);

  const int tid = threadIdx.x;
  const int lane = tid & 63, wid = tid >> 6;
  const int wm = (wid >> 1) << 6, wn = (wid & 1) << 5;
  const int lr = lane & 15, lg = lane >> 4;
  const int isbf = sniff_bf16(xraw);
#pragma unroll
  for (int i = 0; i < 4; ++i) {
#pragma unroll
    for (int r = 0; r < 4; ++r) {
      const int m = m0 + wm + i * 16 + lg * 4 + r;
#pragma unroll
      for (int j = 0; j < 2; ++j) {
        const int n = n0 + wn + j * 16 + lr;
        const float v = acc[i][j][r] + (float)bp[n];
        const size_t idx = ((size_t)m << 10) | (size_t)n;
        if (isbf) ((bf16*)out)[idx] = (bf16)v;
        else      ((float*)out)[idx] = v;
      }
    }
  }
}

extern "C" void kernel_launch(void* const* d_in, const int* in_sizes, int n_in,
                              void* d_out, int out_size, void* d_ws, size_t ws_size,
                              hipStream_t stream) {
  (void)in_sizes; (void)n_in; (void)out_size;
  if (ws_size < (50u << 20)) return;

  char* ws = (char*)d_ws;
  bf16* q_ws  = (bf16*)(ws);                        // 8 MiB frag-order Q (pre-scaled)
  bf16* k_ws  = (bf16*)(ws + (8u << 20));           // 8 MiB frag-order K
  bf16* vt_ws = (bf16*)(ws + (16u << 20));          // 8 MiB frag-order V^T
  bf16* a_ws  = (bf16*)(ws + (24u << 20));          // 8 MiB row-major attn out
  bf16* xc    = (bf16*)(ws + (32u << 20));          // 8 MiB canonical x
  bf16* Wqc   = (bf16*)(ws + (40u << 20));          // 2 MiB each
  bf16* Wkc   = (bf16*)(ws + (42u << 20));
  bf16* Wvc   = (bf16*)(ws + (44u << 20));
  bf16* Wpc   = (bf16*)(ws + (46u << 20));
  bf16* bpc   = (bf16*)(ws + (48u << 20));

  ConvArgs ca;
  ca.src[0] = d_in[0]; ca.dst[0] = xc;  ca.n[0] = 4096 * 1024;
  ca.src[1] = d_in[1]; ca.dst[1] = Wqc; ca.n[1] = 1024 * 1024;
  ca.src[2] = d_in[2]; ca.dst[2] = Wkc; ca.n[2] = 1024 * 1024;
  ca.src[3] = d_in[3]; ca.dst[3] = Wvc; ca.n[3] = 1024 * 1024;
  ca.src[4] = d_in[4]; ca.dst[4] = Wpc; ca.n[4] = 1024 * 1024;
  ca.src[5] = d_in[5]; ca.dst[5] = bpc; ca.n[5] = 1024;
  convert_kernel<<<dim3(512, 6), 256, 0, stream>>>(ca);

  qkv_proj_kernel<<<768, 256, 0, stream>>>(xc, Wqc, Wkc, Wvc, q_ws, k_ws, vt_ws);
  attn_kernel<<<1024, 256, 0, stream>>>(q_ws, k_ws, vt_ws, a_ws);
  out_proj_kernel<<<512, 256, 0, stream>>>(a_ws, Wpc, bpc, d_out,
                                           (const unsigned short*)d_in[0]);
}

// Round 10
// 178.425 us; speedup vs baseline: 1.3729x; 1.0004x over previous
//
#include <hip/hip_runtime.h>

typedef __bf16 bf16;
typedef __bf16 bf16x8 __attribute__((ext_vector_type(8)));
typedef float f32x4 __attribute__((ext_vector_type(4)));

typedef __attribute__((address_space(1))) const void as1_void;
typedef __attribute__((address_space(3))) void as3_void;

#define DEV __device__ __forceinline__
#define NEG_BIG (-1.0e30f)

// B=2, T=2048, C=1024, H=16, D=64; M = B*T = 4096

DEV void async_load16(const void* g, void* l) {
  __builtin_amdgcn_global_load_lds((as1_void*)g, (as3_void*)l, 16, 0, 0);
}
DEV bf16x8 load8(const bf16* p) { bf16x8 v; __builtin_memcpy(&v, p, 16); return v; }
DEV void store8(bf16* p, bf16x8 v) { __builtin_memcpy(p, &v, 16); }
// raw v_exp_f32 (2^x). Non-volatile asm: schedulable, kept live by use.
DEV float fexp2(float x) { float r; asm("v_exp_f32 %0, %1" : "=v"(r) : "v"(x)); return r; }

// ---------------- in-kernel dtype sniff (block-uniform, deterministic) ----------------
DEV int sniff_bf16(const unsigned short* __restrict__ xr) {
  const int lane = threadIdx.x & 63;
  const unsigned short w = xr[lane * 2];
  const int e = (w >> 7) & 0xFF;
  const bool sane = ((w & 0x7FFF) == 0) || (e >= 97 && e <= 157);
  return __popcll(__ballot(sane)) >= 48;
}

// ---------------- input canonicalization (-> bf16, row-major) ----------------
struct ConvArgs {
  const void* src[6];
  bf16* dst[6];
  int n[6];
};

__global__ __launch_bounds__(256) void convert_kernel(ConvArgs a) {
  const int isbf = sniff_bf16((const unsigned short*)a.src[0]);
  const int t = blockIdx.y;
  const int n = a.n[t];
  bf16* d = a.dst[t];
  const int stride = gridDim.x * 256 * 8;
  if (isbf) {
    const bf16* s = (const bf16*)a.src[t];
    for (int i = (blockIdx.x * 256 + threadIdx.x) * 8; i < n; i += stride)
      store8(d + i, load8(s + i));
  } else {
    const float* s = (const float*)a.src[t];
    for (int i = (blockIdx.x * 256 + threadIdx.x) * 8; i < n; i += stride) {
      float tmp[8];
      __builtin_memcpy(tmp, s + i, 32);
      bf16x8 v;
#pragma unroll
      for (int j = 0; j < 8; ++j) v[j] = (bf16)tmp[j];
      store8(d + i, v);
    }
  }
}

// ---------------- GEMM core v3: BK=32, 3 LDS buffers, 1 barrier/K-tile ----------------
// Verified r3/r7/r9: qkv at 43 us, MfmaUtil 23%, ~1076 cy/step (occupancy-
// invariant: out_proj at 2 blocks/CU shows the same per-step cost -> the
// 2-phase chain is structural, not occupancy-limited). r8's A-direct hybrid
// REGRESSED (66.8 us): register-dep loads consumed in the same step stall.
DEV void gemm_core_128_p(const bf16* A, const bf16* W, const int K, int m0, int n0,
                         f32x4 (&acc)[4][4]) {
  __shared__ alignas(16) bf16 As[3][128 * 32];
  __shared__ alignas(16) bf16 Bs[3][128 * 32];
  const int tid = threadIdx.x;
  const int lane = tid & 63;
  const int wid = tid >> 6;
  const int wm = (wid >> 1) << 6;
  const int wn = (wid & 1) << 6;
  const int lr = lane & 15;
  const int lg = lane >> 4;

  size_t srcA[2], srcB[2];
  int ldsoff[2];
#pragma unroll
  for (int it = 0; it < 2; ++it) {
    const int lin = it * 256 + tid;        // 16B chunk id, 0..511
    const int lr2 = lin >> 3, c = lin & 7;
    const int u = c ^ (lr2 & 7);
    const int r = lr2 * 2 + (u >> 2);      // source row 0..127
    const int g = u & 3;                   // source k-group (8 elems)
    srcA[it] = (size_t)(m0 + r) * K + (size_t)(g * 8);
    srcB[it] = (size_t)(n0 + r) * K + (size_t)(g * 8);
    ldsoff[it] = lin * 8;
  }
  int offA[4], offB[4];
#pragma unroll
  for (int i = 0; i < 4; ++i) {
    const int r = wm + i * 16 + lr;
    const int cc = (lg | ((r & 1) << 2)) ^ ((r >> 1) & 7);
    offA[i] = (((r >> 1) << 3) | cc) * 8;
  }
#pragma unroll
  for (int j = 0; j < 4; ++j) {
    const int r = wn + j * 16 + lr;
    const int cc = (lg | ((r & 1) << 2)) ^ ((r >> 1) & 7);
    offB[j] = (((r >> 1) << 3) | cc) * 8;
  }

  const f32x4 zero = {0.f, 0.f, 0.f, 0.f};
#pragma unroll
  for (int i = 0; i < 4; ++i)
#pragma unroll
    for (int j = 0; j < 4; ++j) acc[i][j] = zero;

  const int nt = K >> 5;  // 32

  auto stage = [&](int buf, int t) {
    const size_t k0 = (size_t)(t << 5);
#pragma unroll
    for (int it = 0; it < 2; ++it) {
      async_load16(A + srcA[it] + k0, &As[buf][0] + ldsoff[it]);
      async_load16(W + srcB[it] + k0, &Bs[buf][0] + ldsoff[it]);
    }
  };

  auto compute = [&](int buf) {
    const bf16* as = &As[buf][0];
    const bf16* bs = &Bs[buf][0];
    bf16x8 af[4], bfr[4];
#pragma unroll
    for (int i = 0; i < 4; ++i) af[i] = load8(as + offA[i]);
#pragma unroll
    for (int j = 0; j < 4; ++j) bfr[j] = load8(bs + offB[j]);
    __builtin_amdgcn_s_setprio(1);
#pragma unroll
    for (int i = 0; i < 4; ++i)
#pragma unroll
      for (int j = 0; j < 4; ++j)
        acc[i][j] = __builtin_amdgcn_mfma_f32_16x16x32_bf16(af[i], bfr[j], acc[i][j], 0, 0, 0);
    __builtin_amdgcn_s_setprio(0);
  };

  stage(0, 0);
  stage(1, 1);
  int b0 = 0, b1 = 1, b2 = 2;
  for (int t = 0; t < nt; ++t) {
    if (t + 1 < nt) asm volatile("s_waitcnt vmcnt(4)" ::: "memory");
    else            asm volatile("s_waitcnt vmcnt(0)" ::: "memory");
    __builtin_amdgcn_s_barrier();          // all waves' tile-t portions in LDS
    if (t + 2 < nt) stage(b2, t + 2);      // buffer last read at iter t-1: safe
    compute(b0);
    const int tmp = b0; b0 = b1; b1 = b2; b2 = tmp;
  }
}

// ---------------- GEMM core: 128x64 tile (out_proj, grid 512) -- verified r7 -------
DEV void gemm_core_128x64_p(const bf16* A, const bf16* W, const int K, int m0, int n0,
                            f32x4 (&acc)[4][2]) {
  __shared__ alignas(16) bf16 As[3][128 * 32];
  __shared__ alignas(16) bf16 Bs[3][64 * 32];
  const int tid = threadIdx.x;
  const int lane = tid & 63;
  const int wid = tid >> 6;
  const int wm = (wid >> 1) << 6;
  const int wn = (wid & 1) << 5;
  const int lr = lane & 15;
  const int lg = lane >> 4;

  size_t srcA[2], srcB;
  int ldsoffA[2], ldsoffB;
#pragma unroll
  for (int it = 0; it < 2; ++it) {
    const int lin = it * 256 + tid;        // A: 512 chunks
    const int lr2 = lin >> 3, c = lin & 7;
    const int u = c ^ (lr2 & 7);
    srcA[it] = (size_t)(m0 + lr2 * 2 + (u >> 2)) * K + (size_t)((u & 3) * 8);
    ldsoffA[it] = lin * 8;
  }
  {
    const int lin = tid;                   // B: 256 chunks (64 rows)
    const int lr2 = lin >> 3, c = lin & 7;
    const int u = c ^ (lr2 & 7);
    srcB = (size_t)(n0 + lr2 * 2 + (u >> 2)) * K + (size_t)((u & 3) * 8);
    ldsoffB = lin * 8;
  }
  int offA[4], offB[2];
#pragma unroll
  for (int i = 0; i < 4; ++i) {
    const int r = wm + i * 16 + lr;
    const int cc = (lg | ((r & 1) << 2)) ^ ((r >> 1) & 7);
    offA[i] = (((r >> 1) << 3) | cc) * 8;
  }
#pragma unroll
  for (int j = 0; j < 2; ++j) {
    const int r = wn + j * 16 + lr;
    const int cc = (lg | ((r & 1) << 2)) ^ ((r >> 1) & 7);
    offB[j] = (((r >> 1) << 3) | cc) * 8;
  }

  const f32x4 zero = {0.f, 0.f, 0.f, 0.f};
#pragma unroll
  for (int i = 0; i < 4; ++i)
#pragma unroll
    for (int j = 0; j < 2; ++j) acc[i][j] = zero;

  const int nt = K >> 5;  // 32

  auto stage = [&](int buf, int t) {
    const size_t k0 = (size_t)(t << 5);
#pragma unroll
    for (int it = 0; it < 2; ++it)
      async_load16(A + srcA[it] + k0, &As[buf][0] + ldsoffA[it]);
    async_load16(W + srcB + k0, &Bs[buf][0] + ldsoffB);
  };

  auto compute = [&](int buf) {
    const bf16* as = &As[buf][0];
    const bf16* bs = &Bs[buf][0];
    bf16x8 af[4], bfr[2];
#pragma unroll
    for (int i = 0; i < 4; ++i) af[i] = load8(as + offA[i]);
#pragma unroll
    for (int j = 0; j < 2; ++j) bfr[j] = load8(bs + offB[j]);
    __builtin_amdgcn_s_setprio(1);
#pragma unroll
    for (int i = 0; i < 4; ++i)
#pragma unroll
      for (int j = 0; j < 2; ++j)
        acc[i][j] = __builtin_amdgcn_mfma_f32_16x16x32_bf16(af[i], bfr[j], acc[i][j], 0, 0, 0);
    __builtin_amdgcn_s_setprio(0);
  };

  stage(0, 0);
  stage(1, 1);
  int b0 = 0, b1 = 1, b2 = 2;
  for (int t = 0; t < nt; ++t) {
    if (t + 1 < nt) asm volatile("s_waitcnt vmcnt(3)" ::: "memory");
    else            asm volatile("s_waitcnt vmcnt(0)" ::: "memory");
    __builtin_amdgcn_s_barrier();
    if (t + 2 < nt) stage(b2, t + 2);
    compute(b0);
    const int tmp = b0; b0 = b1; b1 = b2; b2 = tmp;
  }
}

// Fragment-order address for a 64x64 tile, element (row, col):
DEV size_t frag_idx(int row, int col) {
  return ((size_t)(((col >> 5) * 4 + ((row >> 4) & 3)) * 64 + ((col >> 3) & 3) * 16 + (row & 15)) << 3)
         | (size_t)(col & 7);
}

// 1-D grid 768. Q pre-scaled by 0.125*log2(e) so attn uses raw v_exp_f32.
__global__ __launch_bounds__(256) void qkv_proj_kernel(
    const bf16* __restrict__ x, const bf16* __restrict__ Wq,
    const bf16* __restrict__ Wk, const bf16* __restrict__ Wv,
    bf16* __restrict__ q_ws, bf16* __restrict__ k_ws, bf16* __restrict__ vt_ws) {
  const int L = blockIdx.x;
  const int xcd = L & 7;
  const int i2 = L >> 3;                 // 0..95
  const int m0 = (xcd * 4 + (i2 & 3)) << 7;
  const int rest = i2 >> 2;              // 0..23
  const int n0 = (rest & 7) << 7;
  const int mode = rest >> 3;            // 0..2
  const bf16* W = (mode == 0) ? Wq : (mode == 1) ? Wk : Wv;
  f32x4 acc[4][4];
  gemm_core_128_p(x, W, 1024, m0, n0, acc);

  const int tid = threadIdx.x;
  const int lane = tid & 63, wid = tid >> 6;
  const int wm = (wid >> 1) << 6, wn = (wid & 1) << 6;
  const int lr = lane & 15, lg = lane >> 4;
  bf16* out = (mode == 0) ? q_ws : (mode == 1) ? k_ws : vt_ws;
  const float scale = (mode == 0) ? 0.18033688011112042f : 1.0f;  // 0.125*log2e
#pragma unroll
  for (int i = 0; i < 4; ++i) {
#pragma unroll
    for (int r = 0; r < 4; ++r) {
      const int m = m0 + wm + i * 16 + lg * 4 + r;
      const int b = m >> 11, t = m & 2047;
#pragma unroll
      for (int j = 0; j < 4; ++j) {
        const int n = n0 + wn + j * 16 + lr;
        const int h = n >> 6, d = n & 63;
        const float v = acc[i][j][r] * scale;
        const size_t base = ((size_t)(b * 16 + h) << 17) + ((size_t)(t >> 6) << 12);
        const size_t idx = base + ((mode < 2) ? frag_idx(t & 63, d) : frag_idx(d, t & 63));
        out[idx] = (bf16)v;
      }
    }
  }
}

// Flash attention v9: K staged in LDS (2-buffer pipeline, shared by 4 waves),
// V read DIRECT from global per wave. Rationale: r4 (both direct) = 44.4 us,
// bound by 24 TB/s duplicate K+V traffic; v8 (both staged) <=42.8 us, DS-pipe
// ~296 cy/wave-step (floor ~32 us). Hybrid: V-direct halves r4's traffic
// (~12 TB/s, under ceiling) and cuts DS to ~200 cy/step (~22 us floor).
// Unlike r8's failed qkv A-direct (consumed in-step, zero slack), V is issued
// at step top and consumed ~700cy later, after QK MFMA + softmax -> hideable.
// LDS 25.6 KB -> 4 blocks/CU (grid 1024).
__global__ __launch_bounds__(256, 4) void attn_kernel(
    const bf16* __restrict__ q_ws, const bf16* __restrict__ k_ws,
    const bf16* __restrict__ vt_ws, bf16* __restrict__ a_ws) {
  const int L = blockIdx.x;
  const int bh = (L & 7) * 4 + ((L >> 3) & 3);
  const int qt = 31 - (L >> 5);
  const int tid = threadIdx.x;
  const int lane = tid & 63, w = tid >> 6;
  const int lr = lane & 15, lg = lane >> 4;
  const int fo = lg * 16 + lr;

  __shared__ alignas(16) bf16 Ks[2][4096];
  __shared__ alignas(16) bf16 Ps[4][16 * 72];
  bf16* ps = &Ps[w][0];

  const size_t hb = (size_t)bh << 17;
  const int b = bh >> 4, h = bh & 15;
  const f32x4 zero = {0.f, 0.f, 0.f, 0.f};
  const bf16* kbase = k_ws + hb;
  const bf16* vbase = vt_ws + hb;
  const size_t qtb = hb + ((size_t)qt << 12);

  bf16x8 aq[2];
#pragma unroll
  for (int c2 = 0; c2 < 2; ++c2)
    aq[c2] = load8(q_ws + qtb + (size_t)(((c2 * 4 + w) * 64 + fo) << 3));

  f32x4 o_acc[4];
#pragma unroll
  for (int j = 0; j < 4; ++j) o_acc[j] = zero;
  float lsum[4] = {0.f, 0.f, 0.f, 0.f};

  const int nt = qt + 1;
  auto ktof = [&](int s) { return (s == 0) ? qt : (s - 1); };

  auto stage = [&](int buf, int s) {
    const int kt = ktof(s);
    const bf16* kg = kbase + ((size_t)kt << 12);
#pragma unroll
    for (int it = 0; it < 2; ++it) {
      const int lin = it * 256 + tid;
      async_load16(kg + lin * 8, &Ks[buf][0] + lin * 8);
    }
  };

  auto step = [&](int buf, int kt, bool diag) {
    const bf16* ks = &Ks[buf][0];
    const bf16* vg = vbase + ((size_t)kt << 12);
    // issue V loads first: consumed after QK+softmax (~700cy of slack)
    bf16x8 bv[2][4];
#pragma unroll
    for (int c2 = 0; c2 < 2; ++c2)
#pragma unroll
      for (int j = 0; j < 4; ++j)
        bv[c2][j] = load8(vg + (size_t)(((c2 * 4 + j) * 64 + fo) << 3));

    f32x4 s[4];
    __builtin_amdgcn_s_setprio(1);
#pragma unroll
    for (int j = 0; j < 4; ++j) {
      s[j] = __builtin_amdgcn_mfma_f32_16x16x32_bf16(
          aq[0], load8(ks + (size_t)(((0 * 4 + j) * 64 + fo) << 3)), zero, 0, 0, 0);
      s[j] = __builtin_amdgcn_mfma_f32_16x16x32_bf16(
          aq[1], load8(ks + (size_t)(((1 * 4 + j) * 64 + fo) << 3)), s[j], 0, 0, 0);
    }
    __builtin_amdgcn_s_setprio(0);
    float p[4][4];
#pragma unroll
    for (int j = 0; j < 4; ++j) {
#pragma unroll
      for (int r = 0; r < 4; ++r) {
        float v = s[j][r];
        if (diag && (j * 16 + lr) > (w * 16 + lg * 4 + r)) v = NEG_BIG;
        p[j][r] = fexp2(v);
      }
    }
#pragma unroll
    for (int r = 0; r < 4; ++r)
      lsum[r] += (p[0][r] + p[1][r]) + (p[2][r] + p[3][r]);
#pragma unroll
    for (int j = 0; j < 4; ++j)
#pragma unroll
      for (int r = 0; r < 4; ++r)
        ps[(lg * 4 + r) * 72 + j * 16 + lr] = (bf16)p[j][r];
    __builtin_amdgcn_s_setprio(1);
#pragma unroll
    for (int c2 = 0; c2 < 2; ++c2) {
      const bf16x8 ap = load8(ps + lr * 72 + c2 * 32 + lg * 8);
#pragma unroll
      for (int j = 0; j < 4; ++j)
        o_acc[j] = __builtin_amdgcn_mfma_f32_16x16x32_bf16(ap, bv[c2][j], o_acc[j], 0, 0, 0);
    }
    __builtin_amdgcn_s_setprio(0);
  };

  // 2-buffer, distance-1, 1 barrier/step (safety argument as v8: any wave
  // past barrier(t) has consumed its step t-1 ds_reads of the buffer).
  stage(0, 0);
  int cur = 0;
  for (int t = 0; t < nt; ++t) {
    asm volatile("s_waitcnt vmcnt(0)" ::: "memory");
    __builtin_amdgcn_s_barrier();
    if (t + 1 < nt) stage(cur ^ 1, t + 1);
    step(cur, ktof(t), t == 0);
    cur ^= 1;
  }

#pragma unroll
  for (int r = 0; r < 4; ++r) {
    float v = lsum[r];
#pragma unroll
    for (int off = 1; off < 16; off <<= 1) v += __shfl_xor(v, off, 64);
    const float inv = 1.f / v;
    const int t = qt * 64 + w * 16 + lg * 4 + r;
#pragma unroll
    for (int j = 0; j < 4; ++j) {
      const size_t idx = (((size_t)(b * 2048 + t)) << 10) | (size_t)(h * 64 + j * 16 + lr);
      a_ws[idx] = (bf16)(o_acc[j][r] * inv);
    }
  }
}

// out_proj: grid 512, 128x64 tiles (verified r7).
__global__ __launch_bounds__(256) void out_proj_kernel(
    const bf16* __restrict__ A, const bf16* __restrict__ Wp,
    const bf16* __restrict__ bp, void* __restrict__ out,
    const unsigned short* __restrict__ xraw) {
  const int L = blockIdx.x;
  const int xcd = L & 7;
  const int i2 = L >> 3;                 // 0..63
  const int m0 = (xcd * 4 + (i2 & 3)) << 7;
  const int n0 = (i2 >> 2) << 6;
  f32x4 acc[4][2];
  gemm_core_128x64_p(A, Wp, 1024, m0, n0, acc);

  const int tid = threadIdx.x;
  const int lane = tid & 63, wid = tid >> 6;
  const int wm = (wid >> 1) << 6, wn = (wid & 1) << 5;
  const int lr = lane & 15, lg = lane >> 4;
  const int isbf = sniff_bf16(xraw);
#pragma unroll
  for (int i = 0; i < 4; ++i) {
#pragma unroll
    for (int r = 0; r < 4; ++r) {
      const int m = m0 + wm + i * 16 + lg * 4 + r;
#pragma unroll
      for (int j = 0; j < 2; ++j) {
        const int n = n0 + wn + j * 16 + lr;
        const float v = acc[i][j][r] + (float)bp[n];
        const size_t idx = ((size_t)m << 10) | (size_t)n;
        if (isbf) ((bf16*)out)[idx] = (bf16)v;
        else      ((float*)out)[idx] = v;
      }
    }
  }
}

extern "C" void kernel_launch(void* const* d_in, const int* in_sizes, int n_in,
                              void* d_out, int out_size, void* d_ws, size_t ws_size,
                              hipStream_t stream) {
  (void)in_sizes; (void)n_in; (void)out_size;
  if (ws_size < (50u << 20)) return;

  char* ws = (char*)d_ws;
  bf16* q_ws  = (bf16*)(ws);                        // 8 MiB frag-order Q (pre-scaled)
  bf16* k_ws  = (bf16*)(ws + (8u << 20));           // 8 MiB frag-order K
  bf16* vt_ws = (bf16*)(ws + (16u << 20));          // 8 MiB frag-order V^T
  bf16* a_ws  = (bf16*)(ws + (24u << 20));          // 8 MiB row-major attn out
  bf16* xc    = (bf16*)(ws + (32u << 20));          // 8 MiB canonical x
  bf16* Wqc   = (bf16*)(ws + (40u << 20));          // 2 MiB each
  bf16* Wkc   = (bf16*)(ws + (42u << 20));
  bf16* Wvc   = (bf16*)(ws + (44u << 20));
  bf16* Wpc   = (bf16*)(ws + (46u << 20));
  bf16* bpc   = (bf16*)(ws + (48u << 20));

  ConvArgs ca;
  ca.src[0] = d_in[0]; ca.dst[0] = xc;  ca.n[0] = 4096 * 1024;
  ca.src[1] = d_in[1]; ca.dst[1] = Wqc; ca.n[1] = 1024 * 1024;
  ca.src[2] = d_in[2]; ca.dst[2] = Wkc; ca.n[2] = 1024 * 1024;
  ca.src[3] = d_in[3]; ca.dst[3] = Wvc; ca.n[3] = 1024 * 1024;
  ca.src[4] = d_in[4]; ca.dst[4] = Wpc; ca.n[4] = 1024 * 1024;
  ca.src[5] = d_in[5]; ca.dst[5] = bpc; ca.n[5] = 1024;
  convert_kernel<<<dim3(512, 6), 256, 0, stream>>>(ca);

  qkv_proj_kernel<<<768, 256, 0, stream>>>(xc, Wqc, Wkc, Wvc, q_ws, k_ws, vt_ws);
  attn_kernel<<<1024, 256, 0, stream>>>(q_ws, k_ws, vt_ws, a_ws);
  out_proj_kernel<<<512, 256, 0, stream>>>(a_ws, Wpc, bpc, d_out,
                                           (const unsigned short*)d_in[0]);
}